// Round 5
// baseline (488.690 us; speedup 1.0000x reference)
//
#include <hip/hip_runtime.h>
#include <math.h>

#define NP 4096
#define F_IN 64
#define HG 64
#define NC 64
#define NT 32
#define NE 65536
#define HOUT 12
#define LEAKY 0.2f
#define LN_EPS 1e-5f

// ---- DPP reductions ----
template <int CTRL>
__device__ __forceinline__ float dppadd(float v, float x) {   // v + dpp(x); invalid lanes add 0
    int r = __builtin_amdgcn_update_dpp(0, __builtin_bit_cast(int, x), CTRL, 0xF, 0xF, false);
    return v + __builtin_bit_cast(float, r);
}
__device__ __forceinline__ float rowsum16(float v) {   // every lane gets its row-of-16 total
    v = dppadd<0x128>(v, v);   // row_ror:8
    v = dppadd<0x124>(v, v);   // row_ror:4
    v = dppadd<0x122>(v, v);   // row_ror:2
    v = dppadd<0x121>(v, v);   // row_ror:1
    return v;
}
__device__ __forceinline__ float xrowsum(float v) {    // ROW-UNIFORM input only! valid lanes 48-63
    v = dppadd<0x142>(v, v);   // row_bcast:15
    v = dppadd<0x143>(v, v);   // row_bcast:31
    return v;
}
__device__ __forceinline__ float rdlane(float v, int l) {
    return __builtin_bit_cast(float, __builtin_amdgcn_readlane(__builtin_bit_cast(int, v), l));
}
__device__ __forceinline__ float wavered63(float v) {
    v = rowsum16(v);
    v = xrowsum(v);
    return rdlane(v, 63);
}
__device__ __forceinline__ float laneXorSum(float v) { // lane-wise cross-row butterfly (16,32)
    v += __shfl_xor(v, 16, 64);
    v += __shfl_xor(v, 32, 64);
    return v;
}

#define FMA4(Acomp, B, r)                                                     \
    acc[r][0] += (Acomp) * (B).x; acc[r][1] += (Acomp) * (B).y;               \
    acc[r][2] += (Acomp) * (B).z; acc[r][3] += (Acomp) * (B).w;

// ---- K0: zero cnt + pre-transpose W_time/W_res ----
__global__ __launch_bounds__(256) void k_prep(const float* __restrict__ W_time,
        const float* __restrict__ W_res, int* __restrict__ cnt,
        float* __restrict__ wtT, float* __restrict__ wrT) {
    int b = blockIdx.x, tid = threadIdx.x;
    if (b < 512) {
        cnt[b * 256 + tid] = 0;
    } else if (b < 528) {
        int i = (b - 512) * 256 + tid;
        wtT[i] = W_time[(i & 63) * 64 + (i >> 6)];
    } else {
        int i = (b - 528) * 256 + tid;
        wrT[i] = W_res[(i & 63) * 64 + (i >> 6)];
    }
}

// ---- K1: hl|hr = X[p]^T @ [Wl|Wr]; rs = X[p]^T @ W_res^T + b_res ----
__global__ __launch_bounds__(256) void k_hlhr(const float* __restrict__ X,
        const float* __restrict__ Wl, const float* __restrict__ Wr,
        const float* __restrict__ wrT, const float* __restrict__ b_res,
        float* __restrict__ hl, float* __restrict__ hr, float* __restrict__ rs) {
    __shared__ float xs[F_IN][36];
    __shared__ float bk[F_IN][132];
    int p = blockIdx.x, tid = threadIdx.x;
    const float4* Xp = (const float4*)(X + (size_t)p * F_IN * NT);
    for (int i4 = tid; i4 < 512; i4 += 256) {
        int f = i4 >> 3, t0 = (i4 & 7) * 4;
        *(float4*)&xs[f][t0] = Xp[i4];
    }
    for (int i = tid; i < F_IN * HG; i += 256) {
        int f = i >> 6, h = i & 63;
        bk[f][h] = Wl[i];
        bk[f][64 + h] = Wr[i];
    }
    __syncthreads();
    {
        int ng = tid & 31, tg = tid >> 5;
        int n0 = ng * 4, t0 = tg * 4;
        float acc[4][4];
#pragma unroll
        for (int i = 0; i < 4; ++i)
#pragma unroll
            for (int j = 0; j < 4; ++j) acc[i][j] = 0.f;
#pragma unroll 8
        for (int f = 0; f < F_IN; ++f) {
            float4 A = *(const float4*)&xs[f][t0];
            float4 B = *(const float4*)&bk[f][n0];
            FMA4(A.x, B, 0) FMA4(A.y, B, 1) FMA4(A.z, B, 2) FMA4(A.w, B, 3)
        }
#pragma unroll
        for (int i = 0; i < 4; ++i) {
            size_t rb = ((size_t)(t0 + i) * NP + p) * HG;
            float4 v;
            v.x = acc[i][0]; v.y = acc[i][1]; v.z = acc[i][2]; v.w = acc[i][3];
            if (ng < 16) *(float4*)&hl[rb + n0] = v;
            else         *(float4*)&hr[rb + n0 - 64] = v;
        }
    }
    __syncthreads();
    for (int i = tid; i < F_IN * NC; i += 256) bk[i >> 6][i & 63] = wrT[i];
    __syncthreads();
    {
        int cg = tid & 15, tg = tid >> 4;
        int c0 = cg * 4, t0 = tg * 2;
        float4 br4 = *(const float4*)&b_res[c0];
        float a0[4] = {br4.x, br4.y, br4.z, br4.w};
        float a1[4] = {br4.x, br4.y, br4.z, br4.w};
#pragma unroll 8
        for (int f = 0; f < F_IN; ++f) {
            float2 A = *(const float2*)&xs[f][t0];
            float4 B = *(const float4*)&bk[f][c0];
            a0[0] += A.x * B.x; a0[1] += A.x * B.y; a0[2] += A.x * B.z; a0[3] += A.x * B.w;
            a1[0] += A.y * B.x; a1[1] += A.y * B.y; a1[2] += A.y * B.z; a1[3] += A.y * B.w;
        }
        float4 v0; v0.x = a0[0]; v0.y = a0[1]; v0.z = a0[2]; v0.w = a0[3];
        float4 v1; v1.x = a1[0]; v1.y = a1[1]; v1.z = a1[2]; v1.w = a1[3];
        *(float4*)&rs[((size_t)(t0 + 0) * NP + p) * NC + c0] = v0;
        *(float4*)&rs[((size_t)(t0 + 1) * NP + p) * NC + c0] = v1;
    }
}

// ---- K2a: in-degree count (4 edges/thread, int4 loads) ----
__global__ __launch_bounds__(256) void k_count(const int* __restrict__ EI,
                                               int* __restrict__ cnt) {
    int gid = blockIdx.x * 256 + threadIdx.x;   // NT*NE/4 threads
    int t = gid >> 14;
    int e4 = (gid & 16383) * 4;
    int4 d4 = *(const int4*)&EI[(size_t)t * 2 * NE + NE + e4];
    int base = t * NP;
    atomicAdd(&cnt[base + d4.x], 1);
    atomicAdd(&cnt[base + d4.y], 1);
    atomicAdd(&cnt[base + d4.z], 1);
    atomicAdd(&cnt[base + d4.w], 1);
}

// ---- K2b: per-t exclusive scan ----
__global__ __launch_bounds__(256) void k_scan(const int* __restrict__ cnt,
        int* __restrict__ start, int* __restrict__ cursor) {
    __shared__ int ctot[256];
    int t = blockIdx.x, tid = threadIdx.x;
    int vals[16];
    int s = 0;
    int base = t * NP + tid * 16;
#pragma unroll
    for (int k = 0; k < 16; ++k) { int v = cnt[base + k]; vals[k] = s; s += v; }
    ctot[tid] = s;
    __syncthreads();
    int inc = s;
    for (int d = 1; d < 256; d <<= 1) {
        int v = (tid >= d) ? ctot[tid - d] : 0;
        __syncthreads();
        ctot[tid] += v;
        __syncthreads();
    }
    int exc = ctot[tid] - inc;
#pragma unroll
    for (int k = 0; k < 16; ++k) {
        int v = t * NE + exc + vals[k];
        start[base + k] = v;
        cursor[base + k] = v;
    }
}

// ---- K2c: scatter edges into CSR slots (4 edges/thread, int4 loads) ----
__global__ __launch_bounds__(256) void k_fill(const int* __restrict__ EI,
        int* __restrict__ cursor, int* __restrict__ ssrc) {
    int gid = blockIdx.x * 256 + threadIdx.x;
    int t = gid >> 14;
    int e4 = (gid & 16383) * 4;
    size_t eb = (size_t)t * 2 * NE;
    int4 s4 = *(const int4*)&EI[eb + e4];
    int4 d4 = *(const int4*)&EI[eb + NE + e4];
    int base = t * NP;
    int slot;
    slot = atomicAdd(&cursor[base + d4.x], 1); ssrc[slot] = s4.x;
    slot = atomicAdd(&cursor[base + d4.y], 1); ssrc[slot] = s4.y;
    slot = atomicAdd(&cursor[base + d4.z], 1); ssrc[slot] = s4.z;
    slot = atomicAdd(&cursor[base + d4.w], 1); ssrc[slot] = s4.w;
}

// ---- K3: GATv2; wave per dst; 4 rows x 16 lanes process 4 edges at once ----
__global__ __launch_bounds__(256) void k_gat(const float* __restrict__ hl,
        float* __restrict__ hr,
        const int* __restrict__ start, const int* __restrict__ cnt,
        const int* __restrict__ ssrc,
        const float* __restrict__ att, const float* __restrict__ gat_b) {
    int wid = blockIdx.x * 4 + (threadIdx.x >> 6);
    int lane = threadIdx.x & 63;
    int row = lane >> 4;
    int c0 = (lane & 15) * 4;
    int t = wid >> 12;
    int i = wid & 4095;
    size_t nbase = ((size_t)t * NP + i) * HG;
    const float* hlt = hl + (size_t)t * NP * HG;
    float4 r4 = *(const float4*)&hr[nbase + c0];
    float4 at4 = *(const float4*)&att[c0];
    int s0 = start[t * NP + i];
    int deg = cnt[t * NP + i];
    float l = 0.f;
    float4 acc = {0.f, 0.f, 0.f, 0.f};
    for (int j = 0; j < deg; j += 4) {
        int jj = j + row;
        int js = (jj < deg) ? jj : (deg - 1);
        int src = ssrc[s0 + js];
        float4 ha = *(const float4*)&hlt[(size_t)src * HG + c0];
        float4 za;
        za.x = ha.x + r4.x; za.y = ha.y + r4.y; za.z = ha.z + r4.z; za.w = ha.w + r4.w;
        za.x = fmaxf(za.x, LEAKY * za.x);
        za.y = fmaxf(za.y, LEAKY * za.y);
        za.z = fmaxf(za.z, LEAKY * za.z);
        za.w = fmaxf(za.w, LEAKY * za.w);
        float ep = za.x * at4.x + za.y * at4.y + za.z * at4.z + za.w * at4.w;
        float e = rowsum16(ep);
        float w = __expf(e);
        w = (jj < deg) ? w : 0.f;
        l += w;
        acc.x += w * ha.x; acc.y += w * ha.y; acc.z += w * ha.z; acc.w += w * ha.w;
    }
    // lane-wise cross-row butterfly: every lane gets the channel-correct total
    float lt = laneXorSum(l);
    acc.x = laneXorSum(acc.x);
    acc.y = laneXorSum(acc.y);
    acc.z = laneXorSum(acc.z);
    acc.w = laneXorSum(acc.w);
    if (row == 0) {
        float inv = (deg > 0) ? (1.0f / lt) : 0.f;
        float4 gb = *(const float4*)&gat_b[c0];
        float4 o;
        o.x = fmaxf(acc.x * inv + gb.x, 0.f);
        o.y = fmaxf(acc.y * inv + gb.y, 0.f);
        o.z = fmaxf(acc.z * inv + gb.z, 0.f);
        o.w = fmaxf(acc.w * inv + gb.w, 0.f);
        *(float4*)&hr[nbase + c0] = o;
    }
}

// ---- K4: Xhat @ W_timeT (+b_time) + rs, ReLU, LN ----
__global__ __launch_bounds__(256) void k_post(const float* __restrict__ Xhat,
        const float* __restrict__ wtT, const float* __restrict__ b_time,
        const float* __restrict__ rs, const float* __restrict__ ln_g,
        const float* __restrict__ ln_b, float* __restrict__ yn) {
    __shared__ float in_t[64][68];
    __shared__ float bk[64][68];
    int bx = blockIdx.x;
    int t = bx >> 6;
    int p0 = (bx & 63) * 64;
    int tid = threadIdx.x;
    const float4* src = (const float4*)(Xhat + ((size_t)t * NP + p0) * HG);
    for (int i4 = tid; i4 < 1024; i4 += 256) {
        int pp = i4 >> 4, c4 = (i4 & 15) * 4;
        *(float4*)&in_t[pp][c4] = src[i4];
    }
    const float4* wsrc = (const float4*)wtT;
    for (int i4 = tid; i4 < 1024; i4 += 256) {
        int h = i4 >> 4, c4 = (i4 & 15) * 4;
        *(float4*)&bk[h][c4] = wsrc[i4];
    }
    __syncthreads();
    int cg = tid & 15, pg = tid >> 4;
    int c0 = cg * 4, pl = pg * 4;
    float4 bt4 = *(const float4*)&b_time[c0];
    float acc[4][4];
#pragma unroll
    for (int i = 0; i < 4; ++i) {
        acc[i][0] = bt4.x; acc[i][1] = bt4.y; acc[i][2] = bt4.z; acc[i][3] = bt4.w;
    }
#pragma unroll
    for (int k4 = 0; k4 < 16; ++k4) {
        float4 A0 = *(const float4*)&in_t[pl + 0][k4 * 4];
        float4 A1 = *(const float4*)&in_t[pl + 1][k4 * 4];
        float4 A2 = *(const float4*)&in_t[pl + 2][k4 * 4];
        float4 A3 = *(const float4*)&in_t[pl + 3][k4 * 4];
        float4 B0 = *(const float4*)&bk[k4 * 4 + 0][c0];
        FMA4(A0.x, B0, 0) FMA4(A1.x, B0, 1) FMA4(A2.x, B0, 2) FMA4(A3.x, B0, 3)
        float4 B1 = *(const float4*)&bk[k4 * 4 + 1][c0];
        FMA4(A0.y, B1, 0) FMA4(A1.y, B1, 1) FMA4(A2.y, B1, 2) FMA4(A3.y, B1, 3)
        float4 B2 = *(const float4*)&bk[k4 * 4 + 2][c0];
        FMA4(A0.z, B2, 0) FMA4(A1.z, B2, 1) FMA4(A2.z, B2, 2) FMA4(A3.z, B2, 3)
        float4 B3 = *(const float4*)&bk[k4 * 4 + 3][c0];
        FMA4(A0.w, B3, 0) FMA4(A1.w, B3, 1) FMA4(A2.w, B3, 2) FMA4(A3.w, B3, 3)
    }
    float4 lg = *(const float4*)&ln_g[c0];
    float4 lb = *(const float4*)&ln_b[c0];
#pragma unroll
    for (int i = 0; i < 4; ++i) {
        size_t prow = (size_t)t * NP + p0 + pl + i;
        float4 r4 = *(const float4*)&rs[prow * NC + c0];
        float y0 = fmaxf(acc[i][0] + r4.x, 0.f), y1 = fmaxf(acc[i][1] + r4.y, 0.f);
        float y2 = fmaxf(acc[i][2] + r4.z, 0.f), y3 = fmaxf(acc[i][3] + r4.w, 0.f);
        float s = rowsum16(y0 + y1 + y2 + y3);
        float ss = rowsum16(y0 * y0 + y1 * y1 + y2 * y2 + y3 * y3);
        float mu = s * (1.f / 64.f);
        float var = ss * (1.f / 64.f) - mu * mu;
        float rsd = rsqrtf(var + LN_EPS);
        float4 o;
        o.x = (y0 - mu) * rsd * lg.x + lb.x;
        o.y = (y1 - mu) * rsd * lg.y + lb.y;
        o.z = (y2 - mu) * rsd * lg.z + lb.z;
        o.w = (y3 - mu) * rsd * lg.w + lb.w;
        *(float4*)&yn[prow * NC + c0] = o;
    }
}

// ---- K5: out[p,o] = sum_{t,c} yn[t,p,c] * Wf[o,t,c] + bf[o]; wave per p ----
__global__ __launch_bounds__(256) void k_final(const float* __restrict__ yn,
        const float* __restrict__ Wf, const float* __restrict__ bf,
        float* __restrict__ out) {
    int p = blockIdx.x * 4 + (threadIdx.x >> 6);
    int lane = threadIdx.x & 63;
    float acc[HOUT];
#pragma unroll
    for (int o = 0; o < HOUT; ++o) acc[o] = 0.f;
    for (int k = 0; k < NT; ++k) {
        float yv = yn[((size_t)k * NP + p) * NC + lane];
#pragma unroll
        for (int o = 0; o < HOUT; ++o)
            acc[o] += yv * Wf[(size_t)o * NT * NC + k * NC + lane];
    }
#pragma unroll
    for (int o = 0; o < HOUT; ++o) {
        float s = wavered63(acc[o]);
        if (lane == 0) out[p * HOUT + o] = s + bf[o];
    }
}

extern "C" void kernel_launch(void* const* d_in, const int* in_sizes, int n_in,
                              void* d_out, int out_size, void* d_ws, size_t ws_size,
                              hipStream_t stream) {
    const float* X      = (const float*)d_in[0];
    const int*   EI     = (const int*)d_in[1];
    const float* Wl     = (const float*)d_in[2];
    const float* Wr     = (const float*)d_in[3];
    const float* att    = (const float*)d_in[4];
    const float* gat_b  = (const float*)d_in[5];
    const float* W_time = (const float*)d_in[6];
    const float* b_time = (const float*)d_in[7];
    const float* W_res  = (const float*)d_in[8];
    const float* b_res  = (const float*)d_in[9];
    const float* ln_g   = (const float*)d_in[10];
    const float* ln_b   = (const float*)d_in[11];
    const float* Wf     = (const float*)d_in[12];
    const float* bf     = (const float*)d_in[13];
    float* out = (float*)d_out;

    char* ws = (char*)d_ws;
    const size_t MB = 1024 * 1024;
    float* hl   = (float*)(ws);                    // 32 MB (reused as yn)
    float* hr   = (float*)(ws + 32 * MB);          // 32 MB (becomes X_hat)
    float* rs   = (float*)(ws + 64 * MB);          // 32 MB residual
    int*   ssrc = (int*)  (ws + 96 * MB);          // 8 MB
    int*   cnt  = (int*)  (ws + 104 * MB);         // 512 KB
    int*   strt = (int*)  (ws + 104 * MB + 512 * 1024);
    int*   curs = (int*)  (ws + 105 * MB);
    float* wtT  = (float*)(ws + 105 * MB + 512 * 1024);   // 16 KB
    float* wrT  = (float*)(ws + 105 * MB + 512 * 1024 + 16384);
    float* yn   = hl;   // hl dead after k_gat

    k_prep <<<544, 256, 0, stream>>>(W_time, W_res, cnt, wtT, wrT);
    k_hlhr <<<NP, 256, 0, stream>>>(X, Wl, Wr, wrT, b_res, hl, hr, rs);
    k_count<<<(NT * NE / 4) / 256, 256, 0, stream>>>(EI, cnt);
    k_scan <<<NT, 256, 0, stream>>>(cnt, strt, curs);
    k_fill <<<(NT * NE / 4) / 256, 256, 0, stream>>>(EI, curs, ssrc);
    k_gat  <<<(NT * NP) / 4, 256, 0, stream>>>(hl, hr, strt, cnt, ssrc, att, gat_b);
    k_post <<<NT * (NP / 64), 256, 0, stream>>>(hr, wtT, b_time, rs, ln_g, ln_b, yn);
    k_final<<<NP / 4, 256, 0, stream>>>(yn, Wf, bf, out);
}

// Round 6
// 379.816 us; speedup vs baseline: 1.2866x; 1.2866x over previous
//
#include <hip/hip_runtime.h>
#include <math.h>

#define NP 4096
#define F_IN 64
#define HG 64
#define NC 64
#define NT 32
#define NE 65536
#define HOUT 12
#define LEAKY 0.2f
#define LN_EPS 1e-5f

// ---- DPP reductions ----
template <int CTRL>
__device__ __forceinline__ float dppadd(float v, float x) {   // v + dpp(x); invalid lanes add 0
    int r = __builtin_amdgcn_update_dpp(0, __builtin_bit_cast(int, x), CTRL, 0xF, 0xF, false);
    return v + __builtin_bit_cast(float, r);
}
__device__ __forceinline__ float rowsum16(float v) {   // every lane gets its row-of-16 total
    v = dppadd<0x128>(v, v);   // row_ror:8
    v = dppadd<0x124>(v, v);   // row_ror:4
    v = dppadd<0x122>(v, v);   // row_ror:2
    v = dppadd<0x121>(v, v);   // row_ror:1
    return v;
}
__device__ __forceinline__ float xrowsum(float v) {    // ROW-UNIFORM input only! valid lanes 48-63
    v = dppadd<0x142>(v, v);   // row_bcast:15
    v = dppadd<0x143>(v, v);   // row_bcast:31
    return v;
}
__device__ __forceinline__ float rdlane(float v, int l) {
    return __builtin_bit_cast(float, __builtin_amdgcn_readlane(__builtin_bit_cast(int, v), l));
}
__device__ __forceinline__ float wavered63(float v) {
    v = rowsum16(v);
    v = xrowsum(v);
    return rdlane(v, 63);
}
__device__ __forceinline__ float laneXorSum(float v) { // lane-wise cross-row butterfly (16,32)
    v += __shfl_xor(v, 16, 64);
    v += __shfl_xor(v, 32, 64);
    return v;
}

#define FMA4(Acomp, B, r)                                                     \
    acc[r][0] += (Acomp) * (B).x; acc[r][1] += (Acomp) * (B).y;               \
    acc[r][2] += (Acomp) * (B).z; acc[r][3] += (Acomp) * (B).w;

// ---- K0: pre-transpose W_time/W_res (cnt no longer needs zeroing) ----
__global__ __launch_bounds__(256) void k_prep(const float* __restrict__ W_time,
        const float* __restrict__ W_res,
        float* __restrict__ wtT, float* __restrict__ wrT) {
    int b = blockIdx.x, tid = threadIdx.x;
    if (b < 16) {
        int i = b * 256 + tid;
        wtT[i] = W_time[(i & 63) * 64 + (i >> 6)];
    } else {
        int i = (b - 16) * 256 + tid;
        wrT[i] = W_res[(i & 63) * 64 + (i >> 6)];
    }
}

// ---- K1: hl|hr = X[p]^T @ [Wl|Wr]; rs = X[p]^T @ W_res^T + b_res ----
__global__ __launch_bounds__(256) void k_hlhr(const float* __restrict__ X,
        const float* __restrict__ Wl, const float* __restrict__ Wr,
        const float* __restrict__ wrT, const float* __restrict__ b_res,
        float* __restrict__ hl, float* __restrict__ hr, float* __restrict__ rs) {
    __shared__ float xs[F_IN][36];
    __shared__ float bk[F_IN][132];
    int p = blockIdx.x, tid = threadIdx.x;
    const float4* Xp = (const float4*)(X + (size_t)p * F_IN * NT);
    for (int i4 = tid; i4 < 512; i4 += 256) {
        int f = i4 >> 3, t0 = (i4 & 7) * 4;
        *(float4*)&xs[f][t0] = Xp[i4];
    }
    for (int i = tid; i < F_IN * HG; i += 256) {
        int f = i >> 6, h = i & 63;
        bk[f][h] = Wl[i];
        bk[f][64 + h] = Wr[i];
    }
    __syncthreads();
    {
        int ng = tid & 31, tg = tid >> 5;
        int n0 = ng * 4, t0 = tg * 4;
        float acc[4][4];
#pragma unroll
        for (int i = 0; i < 4; ++i)
#pragma unroll
            for (int j = 0; j < 4; ++j) acc[i][j] = 0.f;
#pragma unroll 8
        for (int f = 0; f < F_IN; ++f) {
            float4 A = *(const float4*)&xs[f][t0];
            float4 B = *(const float4*)&bk[f][n0];
            FMA4(A.x, B, 0) FMA4(A.y, B, 1) FMA4(A.z, B, 2) FMA4(A.w, B, 3)
        }
#pragma unroll
        for (int i = 0; i < 4; ++i) {
            size_t rb = ((size_t)(t0 + i) * NP + p) * HG;
            float4 v;
            v.x = acc[i][0]; v.y = acc[i][1]; v.z = acc[i][2]; v.w = acc[i][3];
            if (ng < 16) *(float4*)&hl[rb + n0] = v;
            else         *(float4*)&hr[rb + n0 - 64] = v;
        }
    }
    __syncthreads();
    for (int i = tid; i < F_IN * NC; i += 256) bk[i >> 6][i & 63] = wrT[i];
    __syncthreads();
    {
        int cg = tid & 15, tg = tid >> 4;
        int c0 = cg * 4, t0 = tg * 2;
        float4 br4 = *(const float4*)&b_res[c0];
        float a0[4] = {br4.x, br4.y, br4.z, br4.w};
        float a1[4] = {br4.x, br4.y, br4.z, br4.w};
#pragma unroll 8
        for (int f = 0; f < F_IN; ++f) {
            float2 A = *(const float2*)&xs[f][t0];
            float4 B = *(const float4*)&bk[f][c0];
            a0[0] += A.x * B.x; a0[1] += A.x * B.y; a0[2] += A.x * B.z; a0[3] += A.x * B.w;
            a1[0] += A.y * B.x; a1[1] += A.y * B.y; a1[2] += A.y * B.z; a1[3] += A.y * B.w;
        }
        float4 v0; v0.x = a0[0]; v0.y = a0[1]; v0.z = a0[2]; v0.w = a0[3];
        float4 v1; v1.x = a1[0]; v1.y = a1[1]; v1.z = a1[2]; v1.w = a1[3];
        *(float4*)&rs[((size_t)(t0 + 0) * NP + p) * NC + c0] = v0;
        *(float4*)&rs[((size_t)(t0 + 1) * NP + p) * NC + c0] = v1;
    }
}

// ---- K2a: count; block = (t, 512-dst range); LDS counters, no global atomics ----
__global__ __launch_bounds__(256) void k_count(const int* __restrict__ EI,
                                               int* __restrict__ cnt) {
    __shared__ int loc[512];
    int t = blockIdx.x >> 3, r = blockIdx.x & 7;
    int tid = threadIdx.x;
    loc[tid] = 0;
    loc[tid + 256] = 0;
    __syncthreads();
    int base = r << 9;
    const int4* dstA = (const int4*)(EI + (size_t)t * 2 * NE + NE);
    for (int i = tid; i < NE / 4; i += 256) {
        int4 d = dstA[i];
        if ((d.x >> 9) == r) atomicAdd(&loc[d.x - base], 1);
        if ((d.y >> 9) == r) atomicAdd(&loc[d.y - base], 1);
        if ((d.z >> 9) == r) atomicAdd(&loc[d.z - base], 1);
        if ((d.w >> 9) == r) atomicAdd(&loc[d.w - base], 1);
    }
    __syncthreads();
    cnt[t * NP + base + tid] = loc[tid];
    cnt[t * NP + base + tid + 256] = loc[tid + 256];
}

// ---- K2b: per-t exclusive scan (start only; no cursor array needed) ----
__global__ __launch_bounds__(256) void k_scan(const int* __restrict__ cnt,
        int* __restrict__ start) {
    __shared__ int ctot[256];
    int t = blockIdx.x, tid = threadIdx.x;
    int vals[16];
    int s = 0;
    int base = t * NP + tid * 16;
#pragma unroll
    for (int k = 0; k < 16; ++k) { int v = cnt[base + k]; vals[k] = s; s += v; }
    ctot[tid] = s;
    __syncthreads();
    int inc = s;
    for (int d = 1; d < 256; d <<= 1) {
        int v = (tid >= d) ? ctot[tid - d] : 0;
        __syncthreads();
        ctot[tid] += v;
        __syncthreads();
    }
    int exc = ctot[tid] - inc;
#pragma unroll
    for (int k = 0; k < 16; ++k) {
        start[base + k] = t * NE + exc + vals[k];
    }
}

// ---- K2c: fill; block = (t, 512-dst range); LDS cursors; single-writer region ----
__global__ __launch_bounds__(256) void k_fill(const int* __restrict__ EI,
        const int* __restrict__ strt, int* __restrict__ ssrc) {
    __shared__ int curs_l[512];
    int t = blockIdx.x >> 3, r = blockIdx.x & 7;
    int tid = threadIdx.x;
    int base = r << 9;
    curs_l[tid] = strt[t * NP + base + tid];
    curs_l[tid + 256] = strt[t * NP + base + tid + 256];
    __syncthreads();
    const int4* srcA = (const int4*)(EI + (size_t)t * 2 * NE);
    const int4* dstA = (const int4*)(EI + (size_t)t * 2 * NE + NE);
    for (int i = tid; i < NE / 4; i += 256) {
        int4 s = srcA[i];
        int4 d = dstA[i];
        if ((d.x >> 9) == r) { int sl = atomicAdd(&curs_l[d.x - base], 1); ssrc[sl] = s.x; }
        if ((d.y >> 9) == r) { int sl = atomicAdd(&curs_l[d.y - base], 1); ssrc[sl] = s.y; }
        if ((d.z >> 9) == r) { int sl = atomicAdd(&curs_l[d.z - base], 1); ssrc[sl] = s.z; }
        if ((d.w >> 9) == r) { int sl = atomicAdd(&curs_l[d.w - base], 1); ssrc[sl] = s.w; }
    }
}

// ---- K3: GATv2; wave per dst; 4 rows x 16 lanes process 4 edges at once ----
__global__ __launch_bounds__(256) void k_gat(const float* __restrict__ hl,
        float* __restrict__ hr,
        const int* __restrict__ start, const int* __restrict__ cnt,
        const int* __restrict__ ssrc,
        const float* __restrict__ att, const float* __restrict__ gat_b) {
    int wid = blockIdx.x * 4 + (threadIdx.x >> 6);
    int lane = threadIdx.x & 63;
    int row = lane >> 4;
    int c0 = (lane & 15) * 4;
    int t = wid >> 12;
    int i = wid & 4095;
    size_t nbase = ((size_t)t * NP + i) * HG;
    const float* hlt = hl + (size_t)t * NP * HG;
    float4 r4 = *(const float4*)&hr[nbase + c0];
    float4 at4 = *(const float4*)&att[c0];
    int s0 = start[t * NP + i];
    int deg = cnt[t * NP + i];
    float l = 0.f;
    float4 acc = {0.f, 0.f, 0.f, 0.f};
    for (int j = 0; j < deg; j += 4) {
        int jj = j + row;
        int js = (jj < deg) ? jj : (deg - 1);
        int src = ssrc[s0 + js];
        float4 ha = *(const float4*)&hlt[(size_t)src * HG + c0];
        float4 za;
        za.x = ha.x + r4.x; za.y = ha.y + r4.y; za.z = ha.z + r4.z; za.w = ha.w + r4.w;
        za.x = fmaxf(za.x, LEAKY * za.x);
        za.y = fmaxf(za.y, LEAKY * za.y);
        za.z = fmaxf(za.z, LEAKY * za.z);
        za.w = fmaxf(za.w, LEAKY * za.w);
        float ep = za.x * at4.x + za.y * at4.y + za.z * at4.z + za.w * at4.w;
        float e = rowsum16(ep);
        float w = __expf(e);
        w = (jj < deg) ? w : 0.f;
        l += w;
        acc.x += w * ha.x; acc.y += w * ha.y; acc.z += w * ha.z; acc.w += w * ha.w;
    }
    float lt = laneXorSum(l);
    acc.x = laneXorSum(acc.x);
    acc.y = laneXorSum(acc.y);
    acc.z = laneXorSum(acc.z);
    acc.w = laneXorSum(acc.w);
    if (row == 0) {
        float inv = (deg > 0) ? (1.0f / lt) : 0.f;
        float4 gb = *(const float4*)&gat_b[c0];
        float4 o;
        o.x = fmaxf(acc.x * inv + gb.x, 0.f);
        o.y = fmaxf(acc.y * inv + gb.y, 0.f);
        o.z = fmaxf(acc.z * inv + gb.z, 0.f);
        o.w = fmaxf(acc.w * inv + gb.w, 0.f);
        *(float4*)&hr[nbase + c0] = o;
    }
}

// ---- K4: Xhat @ W_timeT (+b_time) + rs, ReLU, LN ----
__global__ __launch_bounds__(256) void k_post(const float* __restrict__ Xhat,
        const float* __restrict__ wtT, const float* __restrict__ b_time,
        const float* __restrict__ rs, const float* __restrict__ ln_g,
        const float* __restrict__ ln_b, float* __restrict__ yn) {
    __shared__ float in_t[64][68];
    __shared__ float bk[64][68];
    int bx = blockIdx.x;
    int t = bx >> 6;
    int p0 = (bx & 63) * 64;
    int tid = threadIdx.x;
    const float4* src = (const float4*)(Xhat + ((size_t)t * NP + p0) * HG);
    for (int i4 = tid; i4 < 1024; i4 += 256) {
        int pp = i4 >> 4, c4 = (i4 & 15) * 4;
        *(float4*)&in_t[pp][c4] = src[i4];
    }
    const float4* wsrc = (const float4*)wtT;
    for (int i4 = tid; i4 < 1024; i4 += 256) {
        int h = i4 >> 4, c4 = (i4 & 15) * 4;
        *(float4*)&bk[h][c4] = wsrc[i4];
    }
    __syncthreads();
    int cg = tid & 15, pg = tid >> 4;
    int c0 = cg * 4, pl = pg * 4;
    float4 bt4 = *(const float4*)&b_time[c0];
    float acc[4][4];
#pragma unroll
    for (int i = 0; i < 4; ++i) {
        acc[i][0] = bt4.x; acc[i][1] = bt4.y; acc[i][2] = bt4.z; acc[i][3] = bt4.w;
    }
#pragma unroll
    for (int k4 = 0; k4 < 16; ++k4) {
        float4 A0 = *(const float4*)&in_t[pl + 0][k4 * 4];
        float4 A1 = *(const float4*)&in_t[pl + 1][k4 * 4];
        float4 A2 = *(const float4*)&in_t[pl + 2][k4 * 4];
        float4 A3 = *(const float4*)&in_t[pl + 3][k4 * 4];
        float4 B0 = *(const float4*)&bk[k4 * 4 + 0][c0];
        FMA4(A0.x, B0, 0) FMA4(A1.x, B0, 1) FMA4(A2.x, B0, 2) FMA4(A3.x, B0, 3)
        float4 B1 = *(const float4*)&bk[k4 * 4 + 1][c0];
        FMA4(A0.y, B1, 0) FMA4(A1.y, B1, 1) FMA4(A2.y, B1, 2) FMA4(A3.y, B1, 3)
        float4 B2 = *(const float4*)&bk[k4 * 4 + 2][c0];
        FMA4(A0.z, B2, 0) FMA4(A1.z, B2, 1) FMA4(A2.z, B2, 2) FMA4(A3.z, B2, 3)
        float4 B3 = *(const float4*)&bk[k4 * 4 + 3][c0];
        FMA4(A0.w, B3, 0) FMA4(A1.w, B3, 1) FMA4(A2.w, B3, 2) FMA4(A3.w, B3, 3)
    }
    float4 lg = *(const float4*)&ln_g[c0];
    float4 lb = *(const float4*)&ln_b[c0];
#pragma unroll
    for (int i = 0; i < 4; ++i) {
        size_t prow = (size_t)t * NP + p0 + pl + i;
        float4 r4 = *(const float4*)&rs[prow * NC + c0];
        float y0 = fmaxf(acc[i][0] + r4.x, 0.f), y1 = fmaxf(acc[i][1] + r4.y, 0.f);
        float y2 = fmaxf(acc[i][2] + r4.z, 0.f), y3 = fmaxf(acc[i][3] + r4.w, 0.f);
        float s = rowsum16(y0 + y1 + y2 + y3);
        float ss = rowsum16(y0 * y0 + y1 * y1 + y2 * y2 + y3 * y3);
        float mu = s * (1.f / 64.f);
        float var = ss * (1.f / 64.f) - mu * mu;
        float rsd = rsqrtf(var + LN_EPS);
        float4 o;
        o.x = (y0 - mu) * rsd * lg.x + lb.x;
        o.y = (y1 - mu) * rsd * lg.y + lb.y;
        o.z = (y2 - mu) * rsd * lg.z + lb.z;
        o.w = (y3 - mu) * rsd * lg.w + lb.w;
        *(float4*)&yn[prow * NC + c0] = o;
    }
}

// ---- K5: out[p,o] = sum_{t,c} yn[t,p,c] * Wf[o,t,c] + bf[o]; wave per p ----
__global__ __launch_bounds__(256) void k_final(const float* __restrict__ yn,
        const float* __restrict__ Wf, const float* __restrict__ bf,
        float* __restrict__ out) {
    int p = blockIdx.x * 4 + (threadIdx.x >> 6);
    int lane = threadIdx.x & 63;
    float acc[HOUT];
#pragma unroll
    for (int o = 0; o < HOUT; ++o) acc[o] = 0.f;
    for (int k = 0; k < NT; ++k) {
        float yv = yn[((size_t)k * NP + p) * NC + lane];
#pragma unroll
        for (int o = 0; o < HOUT; ++o)
            acc[o] += yv * Wf[(size_t)o * NT * NC + k * NC + lane];
    }
#pragma unroll
    for (int o = 0; o < HOUT; ++o) {
        float s = wavered63(acc[o]);
        if (lane == 0) out[p * HOUT + o] = s + bf[o];
    }
}

extern "C" void kernel_launch(void* const* d_in, const int* in_sizes, int n_in,
                              void* d_out, int out_size, void* d_ws, size_t ws_size,
                              hipStream_t stream) {
    const float* X      = (const float*)d_in[0];
    const int*   EI     = (const int*)d_in[1];
    const float* Wl     = (const float*)d_in[2];
    const float* Wr     = (const float*)d_in[3];
    const float* att    = (const float*)d_in[4];
    const float* gat_b  = (const float*)d_in[5];
    const float* W_time = (const float*)d_in[6];
    const float* b_time = (const float*)d_in[7];
    const float* W_res  = (const float*)d_in[8];
    const float* b_res  = (const float*)d_in[9];
    const float* ln_g   = (const float*)d_in[10];
    const float* ln_b   = (const float*)d_in[11];
    const float* Wf     = (const float*)d_in[12];
    const float* bf     = (const float*)d_in[13];
    float* out = (float*)d_out;

    char* ws = (char*)d_ws;
    const size_t MB = 1024 * 1024;
    float* hl   = (float*)(ws);                    // 32 MB (reused as yn)
    float* hr   = (float*)(ws + 32 * MB);          // 32 MB (becomes X_hat)
    float* rs   = (float*)(ws + 64 * MB);          // 32 MB residual
    int*   ssrc = (int*)  (ws + 96 * MB);          // 8 MB
    int*   cnt  = (int*)  (ws + 104 * MB);         // 512 KB
    int*   strt = (int*)  (ws + 104 * MB + 512 * 1024);
    float* wtT  = (float*)(ws + 105 * MB);         // 16 KB
    float* wrT  = (float*)(ws + 105 * MB + 16384);
    float* yn   = hl;   // hl dead after k_gat

    k_prep <<<32, 256, 0, stream>>>(W_time, W_res, wtT, wrT);
    k_hlhr <<<NP, 256, 0, stream>>>(X, Wl, Wr, wrT, b_res, hl, hr, rs);
    k_count<<<NT * 8, 256, 0, stream>>>(EI, cnt);
    k_scan <<<NT, 256, 0, stream>>>(cnt, strt);
    k_fill <<<NT * 8, 256, 0, stream>>>(EI, strt, ssrc);
    k_gat  <<<(NT * NP) / 4, 256, 0, stream>>>(hl, hr, strt, cnt, ssrc, att, gat_b);
    k_post <<<NT * (NP / 64), 256, 0, stream>>>(hr, wtT, b_time, rs, ln_g, ln_b, yn);
    k_final<<<NP / 4, 256, 0, stream>>>(yn, Wf, bf, out);
}

// Round 7
// 355.356 us; speedup vs baseline: 1.3752x; 1.0688x over previous
//
#include <hip/hip_runtime.h>
#include <math.h>

#define NP 4096
#define F_IN 64
#define HG 64
#define NC 64
#define NT 32
#define NE 65536
#define HOUT 12
#define LEAKY 0.2f
#define LN_EPS 1e-5f

// ---- DPP reductions ----
template <int CTRL>
__device__ __forceinline__ float dppadd(float v, float x) {   // v + dpp(x); invalid lanes add 0
    int r = __builtin_amdgcn_update_dpp(0, __builtin_bit_cast(int, x), CTRL, 0xF, 0xF, false);
    return v + __builtin_bit_cast(float, r);
}
__device__ __forceinline__ float rowsum16(float v) {   // every lane gets its row-of-16 total
    v = dppadd<0x128>(v, v);   // row_ror:8
    v = dppadd<0x124>(v, v);   // row_ror:4
    v = dppadd<0x122>(v, v);   // row_ror:2
    v = dppadd<0x121>(v, v);   // row_ror:1
    return v;
}
__device__ __forceinline__ float xrowsum(float v) {    // ROW-UNIFORM input only! valid lanes 48-63
    v = dppadd<0x142>(v, v);   // row_bcast:15
    v = dppadd<0x143>(v, v);   // row_bcast:31
    return v;
}
__device__ __forceinline__ float rdlane(float v, int l) {
    return __builtin_bit_cast(float, __builtin_amdgcn_readlane(__builtin_bit_cast(int, v), l));
}
__device__ __forceinline__ float wavered63(float v) {
    v = rowsum16(v);
    v = xrowsum(v);
    return rdlane(v, 63);
}
__device__ __forceinline__ float laneXorSum(float v) { // lane-wise cross-row butterfly (16,32)
    v += __shfl_xor(v, 16, 64);
    v += __shfl_xor(v, 32, 64);
    return v;
}

#define FMA4(Acomp, B, r)                                                     \
    acc[r][0] += (Acomp) * (B).x; acc[r][1] += (Acomp) * (B).y;               \
    acc[r][2] += (Acomp) * (B).z; acc[r][3] += (Acomp) * (B).w;

// ---- K0: pre-transpose W_time/W_res ----
__global__ __launch_bounds__(256) void k_prep(const float* __restrict__ W_time,
        const float* __restrict__ W_res,
        float* __restrict__ wtT, float* __restrict__ wrT) {
    int b = blockIdx.x, tid = threadIdx.x;
    if (b < 16) {
        int i = b * 256 + tid;
        wtT[i] = W_time[(i & 63) * 64 + (i >> 6)];
    } else {
        int i = (b - 16) * 256 + tid;
        wrT[i] = W_res[(i & 63) * 64 + (i >> 6)];
    }
}

// ---- K1: hl|hr = X[p]^T @ [Wl|Wr]; rs = X[p]^T @ W_res^T + b_res ----
__global__ __launch_bounds__(256) void k_hlhr(const float* __restrict__ X,
        const float* __restrict__ Wl, const float* __restrict__ Wr,
        const float* __restrict__ wrT, const float* __restrict__ b_res,
        float* __restrict__ hl, float* __restrict__ hr, float* __restrict__ rs) {
    __shared__ float xs[F_IN][36];
    __shared__ float bk[F_IN][132];
    int p = blockIdx.x, tid = threadIdx.x;
    const float4* Xp = (const float4*)(X + (size_t)p * F_IN * NT);
    for (int i4 = tid; i4 < 512; i4 += 256) {
        int f = i4 >> 3, t0 = (i4 & 7) * 4;
        *(float4*)&xs[f][t0] = Xp[i4];
    }
    for (int i = tid; i < F_IN * HG; i += 256) {
        int f = i >> 6, h = i & 63;
        bk[f][h] = Wl[i];
        bk[f][64 + h] = Wr[i];
    }
    __syncthreads();
    {
        int ng = tid & 31, tg = tid >> 5;
        int n0 = ng * 4, t0 = tg * 4;
        float acc[4][4];
#pragma unroll
        for (int i = 0; i < 4; ++i)
#pragma unroll
            for (int j = 0; j < 4; ++j) acc[i][j] = 0.f;
#pragma unroll 8
        for (int f = 0; f < F_IN; ++f) {
            float4 A = *(const float4*)&xs[f][t0];
            float4 B = *(const float4*)&bk[f][n0];
            FMA4(A.x, B, 0) FMA4(A.y, B, 1) FMA4(A.z, B, 2) FMA4(A.w, B, 3)
        }
#pragma unroll
        for (int i = 0; i < 4; ++i) {
            size_t rb = ((size_t)(t0 + i) * NP + p) * HG;
            float4 v;
            v.x = acc[i][0]; v.y = acc[i][1]; v.z = acc[i][2]; v.w = acc[i][3];
            if (ng < 16) *(float4*)&hl[rb + n0] = v;
            else         *(float4*)&hr[rb + n0 - 64] = v;
        }
    }
    __syncthreads();
    for (int i = tid; i < F_IN * NC; i += 256) bk[i >> 6][i & 63] = wrT[i];
    __syncthreads();
    {
        int cg = tid & 15, tg = tid >> 4;
        int c0 = cg * 4, t0 = tg * 2;
        float4 br4 = *(const float4*)&b_res[c0];
        float a0[4] = {br4.x, br4.y, br4.z, br4.w};
        float a1[4] = {br4.x, br4.y, br4.z, br4.w};
#pragma unroll 8
        for (int f = 0; f < F_IN; ++f) {
            float2 A = *(const float2*)&xs[f][t0];
            float4 B = *(const float4*)&bk[f][c0];
            a0[0] += A.x * B.x; a0[1] += A.x * B.y; a0[2] += A.x * B.z; a0[3] += A.x * B.w;
            a1[0] += A.y * B.x; a1[1] += A.y * B.y; a1[2] += A.y * B.z; a1[3] += A.y * B.w;
        }
        float4 v0; v0.x = a0[0]; v0.y = a0[1]; v0.z = a0[2]; v0.w = a0[3];
        float4 v1; v1.x = a1[0]; v1.y = a1[1]; v1.z = a1[2]; v1.w = a1[3];
        *(float4*)&rs[((size_t)(t0 + 0) * NP + p) * NC + c0] = v0;
        *(float4*)&rs[((size_t)(t0 + 1) * NP + p) * NC + c0] = v1;
    }
}

// ---- K2a: count; block = (t, 1024-dst range); LDS counters; XCD-swizzled ----
// grid 128: xcd=b&7, j=b>>3: t = xcd+8*(j&3), r = j>>2 — same-t blocks share an XCD L2
__global__ __launch_bounds__(256) void k_count(const int* __restrict__ EI,
                                               int* __restrict__ cnt) {
    __shared__ int loc[1024];
    int b = blockIdx.x;
    int j = b >> 3;
    int t = (b & 7) + 8 * (j & 3);
    int r = j >> 2;
    int tid = threadIdx.x;
    loc[tid] = 0; loc[tid + 256] = 0; loc[tid + 512] = 0; loc[tid + 768] = 0;
    __syncthreads();
    int base = r << 10;
    const int4* dstA = (const int4*)(EI + (size_t)t * 2 * NE + NE);
    for (int i = tid; i < NE / 4; i += 256) {
        int4 d = dstA[i];
        if ((d.x >> 10) == r) atomicAdd(&loc[d.x - base], 1);
        if ((d.y >> 10) == r) atomicAdd(&loc[d.y - base], 1);
        if ((d.z >> 10) == r) atomicAdd(&loc[d.z - base], 1);
        if ((d.w >> 10) == r) atomicAdd(&loc[d.w - base], 1);
    }
    __syncthreads();
    int o = t * NP + base + tid;
    cnt[o] = loc[tid];
    cnt[o + 256] = loc[tid + 256];
    cnt[o + 512] = loc[tid + 512];
    cnt[o + 768] = loc[tid + 768];
}

// ---- K2b: per-t exclusive scan ----
__global__ __launch_bounds__(256) void k_scan(const int* __restrict__ cnt,
        int* __restrict__ start) {
    __shared__ int ctot[256];
    int t = blockIdx.x, tid = threadIdx.x;
    int vals[16];
    int s = 0;
    int base = t * NP + tid * 16;
#pragma unroll
    for (int k = 0; k < 16; ++k) { int v = cnt[base + k]; vals[k] = s; s += v; }
    ctot[tid] = s;
    __syncthreads();
    int inc = s;
    for (int d = 1; d < 256; d <<= 1) {
        int v = (tid >= d) ? ctot[tid - d] : 0;
        __syncthreads();
        ctot[tid] += v;
        __syncthreads();
    }
    int exc = ctot[tid] - inc;
#pragma unroll
    for (int k = 0; k < 16; ++k) {
        start[base + k] = t * NE + exc + vals[k];
    }
}

// ---- K2c: fill; block = (t, 1024-dst range); LDS cursors; XCD-swizzled ----
__global__ __launch_bounds__(256) void k_fill(const int* __restrict__ EI,
        const int* __restrict__ strt, int* __restrict__ ssrc) {
    __shared__ int curs_l[1024];
    int b = blockIdx.x;
    int j = b >> 3;
    int t = (b & 7) + 8 * (j & 3);
    int r = j >> 2;
    int tid = threadIdx.x;
    int base = r << 10;
    int o = t * NP + base + tid;
    curs_l[tid] = strt[o];
    curs_l[tid + 256] = strt[o + 256];
    curs_l[tid + 512] = strt[o + 512];
    curs_l[tid + 768] = strt[o + 768];
    __syncthreads();
    const int4* srcA = (const int4*)(EI + (size_t)t * 2 * NE);
    const int4* dstA = (const int4*)(EI + (size_t)t * 2 * NE + NE);
    for (int i = tid; i < NE / 4; i += 256) {
        int4 s = srcA[i];
        int4 d = dstA[i];
        if ((d.x >> 10) == r) { int sl = atomicAdd(&curs_l[d.x - base], 1); ssrc[sl] = s.x; }
        if ((d.y >> 10) == r) { int sl = atomicAdd(&curs_l[d.y - base], 1); ssrc[sl] = s.y; }
        if ((d.z >> 10) == r) { int sl = atomicAdd(&curs_l[d.z - base], 1); ssrc[sl] = s.z; }
        if ((d.w >> 10) == r) { int sl = atomicAdd(&curs_l[d.w - base], 1); ssrc[sl] = s.w; }
    }
}

// ---- K3: GATv2; wave per dst; 4 rows x 16 lanes = 4 edges/iter;
//      LDS-staged edge indices; XCD-swizzled so one t per XCD (L2-resident hl) ----
__global__ __launch_bounds__(256) void k_gat(const float* __restrict__ hl,
        float* __restrict__ hr,
        const int* __restrict__ start, const int* __restrict__ cnt,
        const int* __restrict__ ssrc,
        const float* __restrict__ att, const float* __restrict__ gat_b) {
    __shared__ int sidx[4][64];
    int b = blockIdx.x;              // 32768 blocks
    int k = b >> 3;                  // 0..4095
    int t = (b & 7) + 8 * (k >> 10); // one t per XCD at a time
    int ws = threadIdx.x >> 6;
    int i = (k & 1023) * 4 + ws;
    int lane = threadIdx.x & 63;
    int row = lane >> 4;
    int c0 = (lane & 15) * 4;
    size_t nbase = ((size_t)t * NP + i) * HG;
    const float* hlt = hl + (size_t)t * NP * HG;
    float4 r4 = *(const float4*)&hr[nbase + c0];
    float4 at4 = *(const float4*)&att[c0];
    int s0 = start[t * NP + i];
    int deg = cnt[t * NP + i];
    float l = 0.f;
    float4 acc = {0.f, 0.f, 0.f, 0.f};
    for (int base = 0; base < deg; base += 64) {
        int chunk = deg - base;
        chunk = (chunk < 64) ? chunk : 64;
        int stage = (lane < chunk) ? lane : 0;        // pad with edge 0 of chunk
        sidx[ws][lane] = ssrc[s0 + base + stage];      // one coalesced load per chunk
        for (int j = 0; j < chunk; j += 4) {
            int jj = j + row;
            int src = sidx[ws][(jj < chunk) ? jj : 0];
            float4 ha = *(const float4*)&hlt[((size_t)src << 6) + c0];
            float4 za;
            za.x = ha.x + r4.x; za.y = ha.y + r4.y; za.z = ha.z + r4.z; za.w = ha.w + r4.w;
            za.x = fmaxf(za.x, LEAKY * za.x);
            za.y = fmaxf(za.y, LEAKY * za.y);
            za.z = fmaxf(za.z, LEAKY * za.z);
            za.w = fmaxf(za.w, LEAKY * za.w);
            float ep = za.x * at4.x + za.y * at4.y + za.z * at4.z + za.w * at4.w;
            float e = rowsum16(ep);
            float w = __expf(e);
            w = (jj < chunk) ? w : 0.f;
            l += w;
            acc.x += w * ha.x; acc.y += w * ha.y; acc.z += w * ha.z; acc.w += w * ha.w;
        }
    }
    float lt = laneXorSum(l);
    acc.x = laneXorSum(acc.x);
    acc.y = laneXorSum(acc.y);
    acc.z = laneXorSum(acc.z);
    acc.w = laneXorSum(acc.w);
    if (row == 0) {
        float inv = (deg > 0) ? (1.0f / lt) : 0.f;
        float4 gb = *(const float4*)&gat_b[c0];
        float4 o;
        o.x = fmaxf(acc.x * inv + gb.x, 0.f);
        o.y = fmaxf(acc.y * inv + gb.y, 0.f);
        o.z = fmaxf(acc.z * inv + gb.z, 0.f);
        o.w = fmaxf(acc.w * inv + gb.w, 0.f);
        *(float4*)&hr[nbase + c0] = o;
    }
}

// ---- K4: Xhat @ W_timeT (+b_time) + rs, ReLU, LN ----
__global__ __launch_bounds__(256) void k_post(const float* __restrict__ Xhat,
        const float* __restrict__ wtT, const float* __restrict__ b_time,
        const float* __restrict__ rs, const float* __restrict__ ln_g,
        const float* __restrict__ ln_b, float* __restrict__ yn) {
    __shared__ float in_t[64][68];
    __shared__ float bk[64][68];
    int bx = blockIdx.x;
    int t = bx >> 6;
    int p0 = (bx & 63) * 64;
    int tid = threadIdx.x;
    const float4* src = (const float4*)(Xhat + ((size_t)t * NP + p0) * HG);
    for (int i4 = tid; i4 < 1024; i4 += 256) {
        int pp = i4 >> 4, c4 = (i4 & 15) * 4;
        *(float4*)&in_t[pp][c4] = src[i4];
    }
    const float4* wsrc = (const float4*)wtT;
    for (int i4 = tid; i4 < 1024; i4 += 256) {
        int h = i4 >> 4, c4 = (i4 & 15) * 4;
        *(float4*)&bk[h][c4] = wsrc[i4];
    }
    __syncthreads();
    int cg = tid & 15, pg = tid >> 4;
    int c0 = cg * 4, pl = pg * 4;
    float4 bt4 = *(const float4*)&b_time[c0];
    float acc[4][4];
#pragma unroll
    for (int i = 0; i < 4; ++i) {
        acc[i][0] = bt4.x; acc[i][1] = bt4.y; acc[i][2] = bt4.z; acc[i][3] = bt4.w;
    }
#pragma unroll
    for (int k4 = 0; k4 < 16; ++k4) {
        float4 A0 = *(const float4*)&in_t[pl + 0][k4 * 4];
        float4 A1 = *(const float4*)&in_t[pl + 1][k4 * 4];
        float4 A2 = *(const float4*)&in_t[pl + 2][k4 * 4];
        float4 A3 = *(const float4*)&in_t[pl + 3][k4 * 4];
        float4 B0 = *(const float4*)&bk[k4 * 4 + 0][c0];
        FMA4(A0.x, B0, 0) FMA4(A1.x, B0, 1) FMA4(A2.x, B0, 2) FMA4(A3.x, B0, 3)
        float4 B1 = *(const float4*)&bk[k4 * 4 + 1][c0];
        FMA4(A0.y, B1, 0) FMA4(A1.y, B1, 1) FMA4(A2.y, B1, 2) FMA4(A3.y, B1, 3)
        float4 B2 = *(const float4*)&bk[k4 * 4 + 2][c0];
        FMA4(A0.z, B2, 0) FMA4(A1.z, B2, 1) FMA4(A2.z, B2, 2) FMA4(A3.z, B2, 3)
        float4 B3 = *(const float4*)&bk[k4 * 4 + 3][c0];
        FMA4(A0.w, B3, 0) FMA4(A1.w, B3, 1) FMA4(A2.w, B3, 2) FMA4(A3.w, B3, 3)
    }
    float4 lg = *(const float4*)&ln_g[c0];
    float4 lb = *(const float4*)&ln_b[c0];
#pragma unroll
    for (int i = 0; i < 4; ++i) {
        size_t prow = (size_t)t * NP + p0 + pl + i;
        float4 r4 = *(const float4*)&rs[prow * NC + c0];
        float y0 = fmaxf(acc[i][0] + r4.x, 0.f), y1 = fmaxf(acc[i][1] + r4.y, 0.f);
        float y2 = fmaxf(acc[i][2] + r4.z, 0.f), y3 = fmaxf(acc[i][3] + r4.w, 0.f);
        float s = rowsum16(y0 + y1 + y2 + y3);
        float ss = rowsum16(y0 * y0 + y1 * y1 + y2 * y2 + y3 * y3);
        float mu = s * (1.f / 64.f);
        float var = ss * (1.f / 64.f) - mu * mu;
        float rsd = rsqrtf(var + LN_EPS);
        float4 o;
        o.x = (y0 - mu) * rsd * lg.x + lb.x;
        o.y = (y1 - mu) * rsd * lg.y + lb.y;
        o.z = (y2 - mu) * rsd * lg.z + lb.z;
        o.w = (y3 - mu) * rsd * lg.w + lb.w;
        *(float4*)&yn[prow * NC + c0] = o;
    }
}

// ---- K5: out[p,o] = sum_{t,c} yn[t,p,c] * Wf[o,t,c] + bf[o]; wave per p ----
__global__ __launch_bounds__(256) void k_final(const float* __restrict__ yn,
        const float* __restrict__ Wf, const float* __restrict__ bf,
        float* __restrict__ out) {
    int p = blockIdx.x * 4 + (threadIdx.x >> 6);
    int lane = threadIdx.x & 63;
    float acc[HOUT];
#pragma unroll
    for (int o = 0; o < HOUT; ++o) acc[o] = 0.f;
    for (int k = 0; k < NT; ++k) {
        float yv = yn[((size_t)k * NP + p) * NC + lane];
#pragma unroll
        for (int o = 0; o < HOUT; ++o)
            acc[o] += yv * Wf[(size_t)o * NT * NC + k * NC + lane];
    }
#pragma unroll
    for (int o = 0; o < HOUT; ++o) {
        float s = wavered63(acc[o]);
        if (lane == 0) out[p * HOUT + o] = s + bf[o];
    }
}

extern "C" void kernel_launch(void* const* d_in, const int* in_sizes, int n_in,
                              void* d_out, int out_size, void* d_ws, size_t ws_size,
                              hipStream_t stream) {
    const float* X      = (const float*)d_in[0];
    const int*   EI     = (const int*)d_in[1];
    const float* Wl     = (const float*)d_in[2];
    const float* Wr     = (const float*)d_in[3];
    const float* att    = (const float*)d_in[4];
    const float* gat_b  = (const float*)d_in[5];
    const float* W_time = (const float*)d_in[6];
    const float* b_time = (const float*)d_in[7];
    const float* W_res  = (const float*)d_in[8];
    const float* b_res  = (const float*)d_in[9];
    const float* ln_g   = (const float*)d_in[10];
    const float* ln_b   = (const float*)d_in[11];
    const float* Wf     = (const float*)d_in[12];
    const float* bf     = (const float*)d_in[13];
    float* out = (float*)d_out;

    char* ws = (char*)d_ws;
    const size_t MB = 1024 * 1024;
    float* hl   = (float*)(ws);                    // 32 MB (reused as yn)
    float* hr   = (float*)(ws + 32 * MB);          // 32 MB (becomes X_hat)
    float* rs   = (float*)(ws + 64 * MB);          // 32 MB residual
    int*   ssrc = (int*)  (ws + 96 * MB);          // 8 MB
    int*   cnt  = (int*)  (ws + 104 * MB);         // 512 KB
    int*   strt = (int*)  (ws + 104 * MB + 512 * 1024);
    float* wtT  = (float*)(ws + 105 * MB);         // 16 KB
    float* wrT  = (float*)(ws + 105 * MB + 16384);
    float* yn   = hl;   // hl dead after k_gat

    k_prep <<<32, 256, 0, stream>>>(W_time, W_res, wtT, wrT);
    k_hlhr <<<NP, 256, 0, stream>>>(X, Wl, Wr, wrT, b_res, hl, hr, rs);
    k_count<<<128, 256, 0, stream>>>(EI, cnt);
    k_scan <<<NT, 256, 0, stream>>>(cnt, strt);
    k_fill <<<128, 256, 0, stream>>>(EI, strt, ssrc);
    k_gat  <<<(NT * NP) / 4, 256, 0, stream>>>(hl, hr, strt, cnt, ssrc, att, gat_b);
    k_post <<<NT * (NP / 64), 256, 0, stream>>>(hr, wtT, b_time, rs, ln_g, ln_b, yn);
    k_final<<<NP / 4, 256, 0, stream>>>(yn, Wf, bf, out);
}

// Round 8
// 312.083 us; speedup vs baseline: 1.5659x; 1.1387x over previous
//
#include <hip/hip_runtime.h>
#include <math.h>

#define NP 4096
#define F_IN 64
#define HG 64
#define NC 64
#define NT 32
#define NE 65536
#define HOUT 12
#define LEAKY 0.2f
#define LN_EPS 1e-5f

// ---- DPP reductions ----
template <int CTRL>
__device__ __forceinline__ float dppadd(float v, float x) {   // v + dpp(x); invalid lanes add 0
    int r = __builtin_amdgcn_update_dpp(0, __builtin_bit_cast(int, x), CTRL, 0xF, 0xF, false);
    return v + __builtin_bit_cast(float, r);
}
__device__ __forceinline__ float rowsum16(float v) {   // every lane gets its row-of-16 total
    v = dppadd<0x128>(v, v);   // row_ror:8
    v = dppadd<0x124>(v, v);   // row_ror:4
    v = dppadd<0x122>(v, v);   // row_ror:2
    v = dppadd<0x121>(v, v);   // row_ror:1
    return v;
}
__device__ __forceinline__ float xrowsum(float v) {    // ROW-UNIFORM input only! valid lanes 48-63
    v = dppadd<0x142>(v, v);   // row_bcast:15
    v = dppadd<0x143>(v, v);   // row_bcast:31
    return v;
}
__device__ __forceinline__ float rdlane(float v, int l) {
    return __builtin_bit_cast(float, __builtin_amdgcn_readlane(__builtin_bit_cast(int, v), l));
}
__device__ __forceinline__ float wavered63(float v) {
    v = rowsum16(v);
    v = xrowsum(v);
    return rdlane(v, 63);
}
__device__ __forceinline__ float laneXorSum(float v) { // lane-wise cross-row butterfly (16,32)
    v += __shfl_xor(v, 16, 64);
    v += __shfl_xor(v, 32, 64);
    return v;
}

#define FMA4(Acomp, B, r)                                                     \
    acc[r][0] += (Acomp) * (B).x; acc[r][1] += (Acomp) * (B).y;               \
    acc[r][2] += (Acomp) * (B).z; acc[r][3] += (Acomp) * (B).w;

// ---- K0: pre-transpose W_time/W_res ----
__global__ __launch_bounds__(256) void k_prep(const float* __restrict__ W_time,
        const float* __restrict__ W_res,
        float* __restrict__ wtT, float* __restrict__ wrT) {
    int b = blockIdx.x, tid = threadIdx.x;
    if (b < 16) {
        int i = b * 256 + tid;
        wtT[i] = W_time[(i & 63) * 64 + (i >> 6)];
    } else {
        int i = (b - 16) * 256 + tid;
        wrT[i] = W_res[(i & 63) * 64 + (i >> 6)];
    }
}

// ---- K1: hl|hr = X[p]^T @ [Wl|Wr]; rs = X[p]^T @ W_res^T + b_res ----
// B read directly from global (L1/L2-hot, block-invariant): LDS = 9 KB -> high occupancy
__global__ __launch_bounds__(256) void k_hlhr(const float* __restrict__ X,
        const float* __restrict__ Wl, const float* __restrict__ Wr,
        const float* __restrict__ wrT, const float* __restrict__ b_res,
        float* __restrict__ hl, float* __restrict__ hr, float* __restrict__ rs) {
    __shared__ float xs[F_IN][36];
    int p = blockIdx.x, tid = threadIdx.x;
    const float4* Xp = (const float4*)(X + (size_t)p * F_IN * NT);
    for (int i4 = tid; i4 < 512; i4 += 256) {
        int f = i4 >> 3, t0 = (i4 & 7) * 4;
        *(float4*)&xs[f][t0] = Xp[i4];
    }
    __syncthreads();
    {   // loop1: [hl|hr]; thread = 4t x 4n; lanes 0-15 of each 32-group do Wl, 16-31 Wr
        int ng = tid & 31, tg = tid >> 5;
        int col = (ng & 15) * 4, t0 = tg * 4;
        const float4* Bp = (const float4*)(((ng < 16) ? Wl : Wr) + col);  // row stride 16 float4
        float acc[4][4];
#pragma unroll
        for (int i = 0; i < 4; ++i)
#pragma unroll
            for (int j = 0; j < 4; ++j) acc[i][j] = 0.f;
#pragma unroll 8
        for (int f = 0; f < F_IN; ++f) {
            float4 A = *(const float4*)&xs[f][t0];
            float4 B = Bp[f * 16];
            FMA4(A.x, B, 0) FMA4(A.y, B, 1) FMA4(A.z, B, 2) FMA4(A.w, B, 3)
        }
#pragma unroll
        for (int i = 0; i < 4; ++i) {
            size_t rb = ((size_t)(t0 + i) * NP + p) * HG;
            float4 v;
            v.x = acc[i][0]; v.y = acc[i][1]; v.z = acc[i][2]; v.w = acc[i][3];
            if (ng < 16) *(float4*)&hl[rb + col] = v;
            else         *(float4*)&hr[rb + col] = v;
        }
    }
    {   // loop2: rs; thread = 2t x 4c
        int cg = tid & 15, tg = tid >> 4;
        int c0 = cg * 4, t0 = tg * 2;
        const float4* Bp = (const float4*)(wrT + c0);
        float4 br4 = *(const float4*)&b_res[c0];
        float a0[4] = {br4.x, br4.y, br4.z, br4.w};
        float a1[4] = {br4.x, br4.y, br4.z, br4.w};
#pragma unroll 8
        for (int f = 0; f < F_IN; ++f) {
            float2 A = *(const float2*)&xs[f][t0];
            float4 B = Bp[f * 16];
            a0[0] += A.x * B.x; a0[1] += A.x * B.y; a0[2] += A.x * B.z; a0[3] += A.x * B.w;
            a1[0] += A.y * B.x; a1[1] += A.y * B.y; a1[2] += A.y * B.z; a1[3] += A.y * B.w;
        }
        float4 v0; v0.x = a0[0]; v0.y = a0[1]; v0.z = a0[2]; v0.w = a0[3];
        float4 v1; v1.x = a1[0]; v1.y = a1[1]; v1.z = a1[2]; v1.w = a1[3];
        *(float4*)&rs[((size_t)(t0 + 0) * NP + p) * NC + c0] = v0;
        *(float4*)&rs[((size_t)(t0 + 1) * NP + p) * NC + c0] = v1;
    }
}

// ---- CSR build, two-level: block = (t, chunk c of NE/4 edges, range r of 1024 dsts)
// grid 512; xcd = b&7 pins all blocks of a t to one XCD L2.
// b: j=b>>3; t=(b&7)+8*(j&3); cr=j>>2: c=cr&3, r=cr>>2

// ---- K2a: per-(t,c,r) counts into cnt2[t][c][d] ----
__global__ __launch_bounds__(256) void k_count(const int* __restrict__ EI,
                                               int* __restrict__ cnt2) {
    __shared__ int loc[1024];
    int b = blockIdx.x;
    int j = b >> 3;
    int t = (b & 7) + 8 * (j & 3);
    int cr = j >> 2;
    int c = cr & 3, r = cr >> 2;
    int tid = threadIdx.x;
    loc[tid] = 0; loc[tid + 256] = 0; loc[tid + 512] = 0; loc[tid + 768] = 0;
    __syncthreads();
    int base = r << 10;
    const int4* dstA = (const int4*)(EI + (size_t)t * 2 * NE + NE) + c * (NE / 16);
    for (int i = tid; i < NE / 16; i += 256) {
        int4 d = dstA[i];
        if ((d.x >> 10) == r) atomicAdd(&loc[d.x - base], 1);
        if ((d.y >> 10) == r) atomicAdd(&loc[d.y - base], 1);
        if ((d.z >> 10) == r) atomicAdd(&loc[d.z - base], 1);
        if ((d.w >> 10) == r) atomicAdd(&loc[d.w - base], 1);
    }
    __syncthreads();
    int o = (t * 4 + c) * NP + base + tid;
    cnt2[o] = loc[tid];
    cnt2[o + 256] = loc[tid + 256];
    cnt2[o + 512] = loc[tid + 512];
    cnt2[o + 768] = loc[tid + 768];
}

// ---- K2b: per-t scan: deg, start, and per-chunk start2 ----
__global__ __launch_bounds__(256) void k_scan(const int* __restrict__ cnt2,
        int* __restrict__ cnt, int* __restrict__ start, int* __restrict__ start2) {
    __shared__ int ctot[256];
    int t = blockIdx.x, tid = threadIdx.x;
    int vals[16];
    int s = 0;
    int dbase = tid * 16;
#pragma unroll
    for (int k = 0; k < 16; ++k) {
        int d = dbase + k;
        int deg = cnt2[(t * 4 + 0) * NP + d] + cnt2[(t * 4 + 1) * NP + d]
                + cnt2[(t * 4 + 2) * NP + d] + cnt2[(t * 4 + 3) * NP + d];
        cnt[t * NP + d] = deg;
        vals[k] = s; s += deg;
    }
    ctot[tid] = s;
    __syncthreads();
    int inc = s;
    for (int dd = 1; dd < 256; dd <<= 1) {
        int v = (tid >= dd) ? ctot[tid - dd] : 0;
        __syncthreads();
        ctot[tid] += v;
        __syncthreads();
    }
    int exc = ctot[tid] - inc;
#pragma unroll
    for (int k = 0; k < 16; ++k) {
        int d = dbase + k;
        int st = t * NE + exc + vals[k];
        start[t * NP + d] = st;
        int q0 = cnt2[(t * 4 + 0) * NP + d];
        int q1 = cnt2[(t * 4 + 1) * NP + d];
        int q2 = cnt2[(t * 4 + 2) * NP + d];
        start2[(t * 4 + 0) * NP + d] = st; st += q0;
        start2[(t * 4 + 1) * NP + d] = st; st += q1;
        start2[(t * 4 + 2) * NP + d] = st; st += q2;
        start2[(t * 4 + 3) * NP + d] = st;
    }
}

// ---- K2c: fill from per-(t,c) cursors; block-local LDS atomics only ----
__global__ __launch_bounds__(256) void k_fill(const int* __restrict__ EI,
        const int* __restrict__ start2, int* __restrict__ ssrc) {
    __shared__ int curs_l[1024];
    int b = blockIdx.x;
    int j = b >> 3;
    int t = (b & 7) + 8 * (j & 3);
    int cr = j >> 2;
    int c = cr & 3, r = cr >> 2;
    int tid = threadIdx.x;
    int base = r << 10;
    int o = (t * 4 + c) * NP + base + tid;
    curs_l[tid] = start2[o];
    curs_l[tid + 256] = start2[o + 256];
    curs_l[tid + 512] = start2[o + 512];
    curs_l[tid + 768] = start2[o + 768];
    __syncthreads();
    const int4* srcA = (const int4*)(EI + (size_t)t * 2 * NE) + c * (NE / 16);
    const int4* dstA = (const int4*)(EI + (size_t)t * 2 * NE + NE) + c * (NE / 16);
    for (int i = tid; i < NE / 16; i += 256) {
        int4 s = srcA[i];
        int4 d = dstA[i];
        if ((d.x >> 10) == r) { int sl = atomicAdd(&curs_l[d.x - base], 1); ssrc[sl] = s.x; }
        if ((d.y >> 10) == r) { int sl = atomicAdd(&curs_l[d.y - base], 1); ssrc[sl] = s.y; }
        if ((d.z >> 10) == r) { int sl = atomicAdd(&curs_l[d.z - base], 1); ssrc[sl] = s.z; }
        if ((d.w >> 10) == r) { int sl = atomicAdd(&curs_l[d.w - base], 1); ssrc[sl] = s.w; }
    }
}

// ---- K3: GATv2; wave per dst; 4 rows x 16 lanes = 4 edges/iter;
//      LDS-staged edge indices; XCD-swizzled so one t per XCD (L2-resident hl) ----
__global__ __launch_bounds__(256) void k_gat(const float* __restrict__ hl,
        float* __restrict__ hr,
        const int* __restrict__ start, const int* __restrict__ cnt,
        const int* __restrict__ ssrc,
        const float* __restrict__ att, const float* __restrict__ gat_b) {
    __shared__ int sidx[4][64];
    int b = blockIdx.x;              // 32768 blocks
    int k = b >> 3;                  // 0..4095
    int t = (b & 7) + 8 * (k >> 10); // one t per XCD at a time
    int ws = threadIdx.x >> 6;
    int i = (k & 1023) * 4 + ws;
    int lane = threadIdx.x & 63;
    int row = lane >> 4;
    int c0 = (lane & 15) * 4;
    size_t nbase = ((size_t)t * NP + i) * HG;
    const float* hlt = hl + (size_t)t * NP * HG;
    float4 r4 = *(const float4*)&hr[nbase + c0];
    float4 at4 = *(const float4*)&att[c0];
    int s0 = start[t * NP + i];
    int deg = cnt[t * NP + i];
    float l = 0.f;
    float4 acc = {0.f, 0.f, 0.f, 0.f};
    for (int base = 0; base < deg; base += 64) {
        int chunk = deg - base;
        chunk = (chunk < 64) ? chunk : 64;
        int stage = (lane < chunk) ? lane : 0;        // pad with edge 0 of chunk
        sidx[ws][lane] = ssrc[s0 + base + stage];      // one coalesced load per chunk
        for (int j = 0; j < chunk; j += 4) {
            int jj = j + row;
            int src = sidx[ws][(jj < chunk) ? jj : 0];
            float4 ha = *(const float4*)&hlt[((size_t)src << 6) + c0];
            float4 za;
            za.x = ha.x + r4.x; za.y = ha.y + r4.y; za.z = ha.z + r4.z; za.w = ha.w + r4.w;
            za.x = fmaxf(za.x, LEAKY * za.x);
            za.y = fmaxf(za.y, LEAKY * za.y);
            za.z = fmaxf(za.z, LEAKY * za.z);
            za.w = fmaxf(za.w, LEAKY * za.w);
            float ep = za.x * at4.x + za.y * at4.y + za.z * at4.z + za.w * at4.w;
            float e = rowsum16(ep);
            float w = __expf(e);
            w = (jj < chunk) ? w : 0.f;
            l += w;
            acc.x += w * ha.x; acc.y += w * ha.y; acc.z += w * ha.z; acc.w += w * ha.w;
        }
    }
    float lt = laneXorSum(l);
    acc.x = laneXorSum(acc.x);
    acc.y = laneXorSum(acc.y);
    acc.z = laneXorSum(acc.z);
    acc.w = laneXorSum(acc.w);
    if (row == 0) {
        float inv = (deg > 0) ? (1.0f / lt) : 0.f;
        float4 gb = *(const float4*)&gat_b[c0];
        float4 o;
        o.x = fmaxf(acc.x * inv + gb.x, 0.f);
        o.y = fmaxf(acc.y * inv + gb.y, 0.f);
        o.z = fmaxf(acc.z * inv + gb.z, 0.f);
        o.w = fmaxf(acc.w * inv + gb.w, 0.f);
        *(float4*)&hr[nbase + c0] = o;
    }
}

// ---- K4: Xhat @ W_timeT (+b_time) + rs, ReLU, LN ----
__global__ __launch_bounds__(256) void k_post(const float* __restrict__ Xhat,
        const float* __restrict__ wtT, const float* __restrict__ b_time,
        const float* __restrict__ rs, const float* __restrict__ ln_g,
        const float* __restrict__ ln_b, float* __restrict__ yn) {
    __shared__ float in_t[64][68];
    __shared__ float bk[64][68];
    int bx = blockIdx.x;
    int t = bx >> 6;
    int p0 = (bx & 63) * 64;
    int tid = threadIdx.x;
    const float4* src = (const float4*)(Xhat + ((size_t)t * NP + p0) * HG);
    for (int i4 = tid; i4 < 1024; i4 += 256) {
        int pp = i4 >> 4, c4 = (i4 & 15) * 4;
        *(float4*)&in_t[pp][c4] = src[i4];
    }
    const float4* wsrc = (const float4*)wtT;
    for (int i4 = tid; i4 < 1024; i4 += 256) {
        int h = i4 >> 4, c4 = (i4 & 15) * 4;
        *(float4*)&bk[h][c4] = wsrc[i4];
    }
    __syncthreads();
    int cg = tid & 15, pg = tid >> 4;
    int c0 = cg * 4, pl = pg * 4;
    float4 bt4 = *(const float4*)&b_time[c0];
    float acc[4][4];
#pragma unroll
    for (int i = 0; i < 4; ++i) {
        acc[i][0] = bt4.x; acc[i][1] = bt4.y; acc[i][2] = bt4.z; acc[i][3] = bt4.w;
    }
#pragma unroll
    for (int k4 = 0; k4 < 16; ++k4) {
        float4 A0 = *(const float4*)&in_t[pl + 0][k4 * 4];
        float4 A1 = *(const float4*)&in_t[pl + 1][k4 * 4];
        float4 A2 = *(const float4*)&in_t[pl + 2][k4 * 4];
        float4 A3 = *(const float4*)&in_t[pl + 3][k4 * 4];
        float4 B0 = *(const float4*)&bk[k4 * 4 + 0][c0];
        FMA4(A0.x, B0, 0) FMA4(A1.x, B0, 1) FMA4(A2.x, B0, 2) FMA4(A3.x, B0, 3)
        float4 B1 = *(const float4*)&bk[k4 * 4 + 1][c0];
        FMA4(A0.y, B1, 0) FMA4(A1.y, B1, 1) FMA4(A2.y, B1, 2) FMA4(A3.y, B1, 3)
        float4 B2 = *(const float4*)&bk[k4 * 4 + 2][c0];
        FMA4(A0.z, B2, 0) FMA4(A1.z, B2, 1) FMA4(A2.z, B2, 2) FMA4(A3.z, B2, 3)
        float4 B3 = *(const float4*)&bk[k4 * 4 + 3][c0];
        FMA4(A0.w, B3, 0) FMA4(A1.w, B3, 1) FMA4(A2.w, B3, 2) FMA4(A3.w, B3, 3)
    }
    float4 lg = *(const float4*)&ln_g[c0];
    float4 lb = *(const float4*)&ln_b[c0];
#pragma unroll
    for (int i = 0; i < 4; ++i) {
        size_t prow = (size_t)t * NP + p0 + pl + i;
        float4 r4 = *(const float4*)&rs[prow * NC + c0];
        float y0 = fmaxf(acc[i][0] + r4.x, 0.f), y1 = fmaxf(acc[i][1] + r4.y, 0.f);
        float y2 = fmaxf(acc[i][2] + r4.z, 0.f), y3 = fmaxf(acc[i][3] + r4.w, 0.f);
        float s = rowsum16(y0 + y1 + y2 + y3);
        float ss = rowsum16(y0 * y0 + y1 * y1 + y2 * y2 + y3 * y3);
        float mu = s * (1.f / 64.f);
        float var = ss * (1.f / 64.f) - mu * mu;
        float rsd = rsqrtf(var + LN_EPS);
        float4 o;
        o.x = (y0 - mu) * rsd * lg.x + lb.x;
        o.y = (y1 - mu) * rsd * lg.y + lb.y;
        o.z = (y2 - mu) * rsd * lg.z + lb.z;
        o.w = (y3 - mu) * rsd * lg.w + lb.w;
        *(float4*)&yn[prow * NC + c0] = o;
    }
}

// ---- K5: out[p,o] = sum_{t,c} yn[t,p,c] * Wf[o,t,c] + bf[o]; wave per p ----
__global__ __launch_bounds__(256) void k_final(const float* __restrict__ yn,
        const float* __restrict__ Wf, const float* __restrict__ bf,
        float* __restrict__ out) {
    int p = blockIdx.x * 4 + (threadIdx.x >> 6);
    int lane = threadIdx.x & 63;
    float acc[HOUT];
#pragma unroll
    for (int o = 0; o < HOUT; ++o) acc[o] = 0.f;
    for (int k = 0; k < NT; ++k) {
        float yv = yn[((size_t)k * NP + p) * NC + lane];
#pragma unroll
        for (int o = 0; o < HOUT; ++o)
            acc[o] += yv * Wf[(size_t)o * NT * NC + k * NC + lane];
    }
#pragma unroll
    for (int o = 0; o < HOUT; ++o) {
        float s = wavered63(acc[o]);
        if (lane == 0) out[p * HOUT + o] = s + bf[o];
    }
}

extern "C" void kernel_launch(void* const* d_in, const int* in_sizes, int n_in,
                              void* d_out, int out_size, void* d_ws, size_t ws_size,
                              hipStream_t stream) {
    const float* X      = (const float*)d_in[0];
    const int*   EI     = (const int*)d_in[1];
    const float* Wl     = (const float*)d_in[2];
    const float* Wr     = (const float*)d_in[3];
    const float* att    = (const float*)d_in[4];
    const float* gat_b  = (const float*)d_in[5];
    const float* W_time = (const float*)d_in[6];
    const float* b_time = (const float*)d_in[7];
    const float* W_res  = (const float*)d_in[8];
    const float* b_res  = (const float*)d_in[9];
    const float* ln_g   = (const float*)d_in[10];
    const float* ln_b   = (const float*)d_in[11];
    const float* Wf     = (const float*)d_in[12];
    const float* bf     = (const float*)d_in[13];
    float* out = (float*)d_out;

    char* ws = (char*)d_ws;
    const size_t MB = 1024 * 1024;
    float* hl    = (float*)(ws);                    // 32 MB (reused as yn)
    float* hr    = (float*)(ws + 32 * MB);          // 32 MB (becomes X_hat)
    float* rs    = (float*)(ws + 64 * MB);          // 32 MB residual
    int*   ssrc  = (int*)  (ws + 96 * MB);          // 8 MB
    int*   cnt   = (int*)  (ws + 104 * MB);         // 512 KB
    int*   strt  = (int*)  (ws + 104 * MB + 512 * 1024);
    float* wtT   = (float*)(ws + 105 * MB);         // 16 KB
    float* wrT   = (float*)(ws + 105 * MB + 16384);
    int*   cnt2  = (int*)  (ws + 106 * MB);         // 2 MB  [t][4][NP]
    int*   strt2 = (int*)  (ws + 108 * MB);         // 2 MB  [t][4][NP]
    float* yn    = hl;   // hl dead after k_gat

    k_prep <<<32, 256, 0, stream>>>(W_time, W_res, wtT, wrT);
    k_hlhr <<<NP, 256, 0, stream>>>(X, Wl, Wr, wrT, b_res, hl, hr, rs);
    k_count<<<512, 256, 0, stream>>>(EI, cnt2);
    k_scan <<<NT, 256, 0, stream>>>(cnt2, cnt, strt, strt2);
    k_fill <<<512, 256, 0, stream>>>(EI, strt2, ssrc);
    k_gat  <<<(NT * NP) / 4, 256, 0, stream>>>(hl, hr, strt, cnt, ssrc, att, gat_b);
    k_post <<<NT * (NP / 64), 256, 0, stream>>>(hr, wtT, b_time, rs, ln_g, ln_b, yn);
    k_final<<<NP / 4, 256, 0, stream>>>(yn, Wf, bf, out);
}

// Round 9
// 290.625 us; speedup vs baseline: 1.6815x; 1.0738x over previous
//
#include <hip/hip_runtime.h>
#include <math.h>

#define NP 4096
#define F_IN 64
#define HG 64
#define NC 64
#define NT 32
#define NE 65536
#define HOUT 12
#define LEAKY 0.2f
#define LN_EPS 1e-5f

// ---- DPP reductions ----
template <int CTRL>
__device__ __forceinline__ float dppadd(float v, float x) {   // v + dpp(x); invalid lanes add 0
    int r = __builtin_amdgcn_update_dpp(0, __builtin_bit_cast(int, x), CTRL, 0xF, 0xF, false);
    return v + __builtin_bit_cast(float, r);
}
__device__ __forceinline__ float rowsum16(float v) {   // every lane gets its row-of-16 total
    v = dppadd<0x128>(v, v);   // row_ror:8
    v = dppadd<0x124>(v, v);   // row_ror:4
    v = dppadd<0x122>(v, v);   // row_ror:2
    v = dppadd<0x121>(v, v);   // row_ror:1
    return v;
}
__device__ __forceinline__ float xrowsum(float v) {    // ROW-UNIFORM input only! valid lanes 48-63
    v = dppadd<0x142>(v, v);   // row_bcast:15
    v = dppadd<0x143>(v, v);   // row_bcast:31
    return v;
}
__device__ __forceinline__ float rdlane(float v, int l) {
    return __builtin_bit_cast(float, __builtin_amdgcn_readlane(__builtin_bit_cast(int, v), l));
}
__device__ __forceinline__ float wavered63(float v) {
    v = rowsum16(v);
    v = xrowsum(v);
    return rdlane(v, 63);
}
__device__ __forceinline__ float laneXorSum(float v) { // lane-wise cross-row butterfly (16,32)
    v += __shfl_xor(v, 16, 64);
    v += __shfl_xor(v, 32, 64);
    return v;
}

#define FMA4(Acomp, B, r)                                                     \
    acc[r][0] += (Acomp) * (B).x; acc[r][1] += (Acomp) * (B).y;               \
    acc[r][2] += (Acomp) * (B).z; acc[r][3] += (Acomp) * (B).w;

// ---- K0: pre-transpose W_time/W_res ----
__global__ __launch_bounds__(256) void k_prep(const float* __restrict__ W_time,
        const float* __restrict__ W_res,
        float* __restrict__ wtT, float* __restrict__ wrT) {
    int b = blockIdx.x, tid = threadIdx.x;
    if (b < 16) {
        int i = b * 256 + tid;
        wtT[i] = W_time[(i & 63) * 64 + (i >> 6)];
    } else {
        int i = (b - 16) * 256 + tid;
        wrT[i] = W_res[(i & 63) * 64 + (i >> 6)];
    }
}

// ---- K1: hl|hr = X[p]^T @ [Wl|Wr]; rs = X[p]^T @ W_res^T + b_res ----
// 2 p per block; B staged in LDS (L1-thrash lesson from R8); 52 KB LDS -> 3 blocks/CU
__global__ __launch_bounds__(256) void k_hlhr(const float* __restrict__ X,
        const float* __restrict__ Wl, const float* __restrict__ Wr,
        const float* __restrict__ wrT, const float* __restrict__ b_res,
        float* __restrict__ hl, float* __restrict__ hr, float* __restrict__ rs) {
    __shared__ float xs[2][F_IN][36];
    __shared__ float bk[F_IN][132];
    int p0 = blockIdx.x * 2, tid = threadIdx.x;
    const float4* Xp = (const float4*)(X + (size_t)p0 * F_IN * NT);
    for (int i4 = tid; i4 < 1024; i4 += 256) {     // both p: coalesced float4
        int pp = i4 >> 9, f = (i4 >> 3) & 63, t0 = (i4 & 7) * 4;
        *(float4*)&xs[pp][f][t0] = Xp[i4];
    }
    for (int i = tid; i < F_IN * HG; i += 256) {
        int f = i >> 6, h = i & 63;
        bk[f][h] = Wl[i];
        bk[f][64 + h] = Wr[i];
    }
    __syncthreads();
    {   // loop1: [hl|hr] for both p; thread = 4t x 4n
        int ng = tid & 31, tg = tid >> 5;
        int n0 = ng * 4, col = (ng & 15) * 4, t0 = tg * 4;
        float acc[8][4];   // [p*4 + t][n]
#pragma unroll
        for (int i = 0; i < 8; ++i)
#pragma unroll
            for (int j = 0; j < 4; ++j) acc[i][j] = 0.f;
#pragma unroll 4
        for (int f = 0; f < F_IN; ++f) {
            float4 B = *(const float4*)&bk[f][n0];
            float4 A0 = *(const float4*)&xs[0][f][t0];
            float4 A1 = *(const float4*)&xs[1][f][t0];
            FMA4(A0.x, B, 0) FMA4(A0.y, B, 1) FMA4(A0.z, B, 2) FMA4(A0.w, B, 3)
            FMA4(A1.x, B, 4) FMA4(A1.y, B, 5) FMA4(A1.z, B, 6) FMA4(A1.w, B, 7)
        }
#pragma unroll
        for (int pp = 0; pp < 2; ++pp) {
#pragma unroll
            for (int i = 0; i < 4; ++i) {
                size_t rb = ((size_t)(t0 + i) * NP + p0 + pp) * HG;
                float4 v;
                v.x = acc[pp * 4 + i][0]; v.y = acc[pp * 4 + i][1];
                v.z = acc[pp * 4 + i][2]; v.w = acc[pp * 4 + i][3];
                if (ng < 16) *(float4*)&hl[rb + col] = v;
                else         *(float4*)&hr[rb + col] = v;
            }
        }
    }
    __syncthreads();
    for (int i = tid; i < F_IN * NC; i += 256) bk[i >> 6][i & 63] = wrT[i];
    __syncthreads();
    {   // loop2: rs for both p; thread = 2t x 4c
        int cg = tid & 15, tg = tid >> 4;
        int c0 = cg * 4, t0 = tg * 2;
        float4 br4 = *(const float4*)&b_res[c0];
        float acc[4][4];   // [p*2 + t][c]
#pragma unroll
        for (int i = 0; i < 4; ++i) {
            acc[i][0] = br4.x; acc[i][1] = br4.y; acc[i][2] = br4.z; acc[i][3] = br4.w;
        }
#pragma unroll 4
        for (int f = 0; f < F_IN; ++f) {
            float4 B = *(const float4*)&bk[f][c0];
            float2 A0 = *(const float2*)&xs[0][f][t0];
            float2 A1 = *(const float2*)&xs[1][f][t0];
            FMA4(A0.x, B, 0) FMA4(A0.y, B, 1)
            FMA4(A1.x, B, 2) FMA4(A1.y, B, 3)
        }
#pragma unroll
        for (int pp = 0; pp < 2; ++pp) {
#pragma unroll
            for (int i = 0; i < 2; ++i) {
                float4 v;
                v.x = acc[pp * 2 + i][0]; v.y = acc[pp * 2 + i][1];
                v.z = acc[pp * 2 + i][2]; v.w = acc[pp * 2 + i][3];
                *(float4*)&rs[((size_t)(t0 + i) * NP + p0 + pp) * NC + c0] = v;
            }
        }
    }
}

// ---- CSR build, two-level: block = (t, chunk c, range r); XCD-pinned per t ----

// ---- K2a: per-(t,c,r) counts into cnt2[t][c][d] ----
__global__ __launch_bounds__(256) void k_count(const int* __restrict__ EI,
                                               int* __restrict__ cnt2) {
    __shared__ int loc[1024];
    int b = blockIdx.x;
    int j = b >> 3;
    int t = (b & 7) + 8 * (j & 3);
    int cr = j >> 2;
    int c = cr & 3, r = cr >> 2;
    int tid = threadIdx.x;
    loc[tid] = 0; loc[tid + 256] = 0; loc[tid + 512] = 0; loc[tid + 768] = 0;
    __syncthreads();
    int base = r << 10;
    const int4* dstA = (const int4*)(EI + (size_t)t * 2 * NE + NE) + c * (NE / 16);
    for (int i = tid; i < NE / 16; i += 256) {
        int4 d = dstA[i];
        if ((d.x >> 10) == r) atomicAdd(&loc[d.x - base], 1);
        if ((d.y >> 10) == r) atomicAdd(&loc[d.y - base], 1);
        if ((d.z >> 10) == r) atomicAdd(&loc[d.z - base], 1);
        if ((d.w >> 10) == r) atomicAdd(&loc[d.w - base], 1);
    }
    __syncthreads();
    int o = (t * 4 + c) * NP + base + tid;
    cnt2[o] = loc[tid];
    cnt2[o + 256] = loc[tid + 256];
    cnt2[o + 512] = loc[tid + 512];
    cnt2[o + 768] = loc[tid + 768];
}

// ---- K2b: per-t scan: deg, start, per-chunk start2 ----
__global__ __launch_bounds__(256) void k_scan(const int* __restrict__ cnt2,
        int* __restrict__ cnt, int* __restrict__ start, int* __restrict__ start2) {
    __shared__ int ctot[256];
    int t = blockIdx.x, tid = threadIdx.x;
    int vals[16];
    int s = 0;
    int dbase = tid * 16;
#pragma unroll
    for (int k = 0; k < 16; ++k) {
        int d = dbase + k;
        int deg = cnt2[(t * 4 + 0) * NP + d] + cnt2[(t * 4 + 1) * NP + d]
                + cnt2[(t * 4 + 2) * NP + d] + cnt2[(t * 4 + 3) * NP + d];
        cnt[t * NP + d] = deg;
        vals[k] = s; s += deg;
    }
    ctot[tid] = s;
    __syncthreads();
    int inc = s;
    for (int dd = 1; dd < 256; dd <<= 1) {
        int v = (tid >= dd) ? ctot[tid - dd] : 0;
        __syncthreads();
        ctot[tid] += v;
        __syncthreads();
    }
    int exc = ctot[tid] - inc;
#pragma unroll
    for (int k = 0; k < 16; ++k) {
        int d = dbase + k;
        int st = t * NE + exc + vals[k];
        start[t * NP + d] = st;
        int q0 = cnt2[(t * 4 + 0) * NP + d];
        int q1 = cnt2[(t * 4 + 1) * NP + d];
        int q2 = cnt2[(t * 4 + 2) * NP + d];
        start2[(t * 4 + 0) * NP + d] = st; st += q0;
        start2[(t * 4 + 1) * NP + d] = st; st += q1;
        start2[(t * 4 + 2) * NP + d] = st; st += q2;
        start2[(t * 4 + 3) * NP + d] = st;
    }
}

// ---- K2c: fill from per-(t,c) cursors; block-local LDS atomics only ----
__global__ __launch_bounds__(256) void k_fill(const int* __restrict__ EI,
        const int* __restrict__ start2, int* __restrict__ ssrc) {
    __shared__ int curs_l[1024];
    int b = blockIdx.x;
    int j = b >> 3;
    int t = (b & 7) + 8 * (j & 3);
    int cr = j >> 2;
    int c = cr & 3, r = cr >> 2;
    int tid = threadIdx.x;
    int base = r << 10;
    int o = (t * 4 + c) * NP + base + tid;
    curs_l[tid] = start2[o];
    curs_l[tid + 256] = start2[o + 256];
    curs_l[tid + 512] = start2[o + 512];
    curs_l[tid + 768] = start2[o + 768];
    __syncthreads();
    const int4* srcA = (const int4*)(EI + (size_t)t * 2 * NE) + c * (NE / 16);
    const int4* dstA = (const int4*)(EI + (size_t)t * 2 * NE + NE) + c * (NE / 16);
    for (int i = tid; i < NE / 16; i += 256) {
        int4 s = srcA[i];
        int4 d = dstA[i];
        if ((d.x >> 10) == r) { int sl = atomicAdd(&curs_l[d.x - base], 1); ssrc[sl] = s.x; }
        if ((d.y >> 10) == r) { int sl = atomicAdd(&curs_l[d.y - base], 1); ssrc[sl] = s.y; }
        if ((d.z >> 10) == r) { int sl = atomicAdd(&curs_l[d.z - base], 1); ssrc[sl] = s.z; }
        if ((d.w >> 10) == r) { int sl = atomicAdd(&curs_l[d.w - base], 1); ssrc[sl] = s.w; }
    }
}

// ---- K3: GATv2; wave per dst; 8 edges/iter (2 independent 4-edge chains) ----
__global__ __launch_bounds__(256) void k_gat(const float* __restrict__ hl,
        float* __restrict__ hr,
        const int* __restrict__ start, const int* __restrict__ cnt,
        const int* __restrict__ ssrc,
        const float* __restrict__ att, const float* __restrict__ gat_b) {
    __shared__ int sidx[4][64];
    int b = blockIdx.x;              // 32768 blocks
    int k = b >> 3;                  // 0..4095
    int t = (b & 7) + 8 * (k >> 10); // one t per XCD at a time
    int ws = threadIdx.x >> 6;
    int i = (k & 1023) * 4 + ws;
    int lane = threadIdx.x & 63;
    int row = lane >> 4;
    int c0 = (lane & 15) * 4;
    size_t nbase = ((size_t)t * NP + i) * HG;
    const float* hlt = hl + (size_t)t * NP * HG;
    float4 r4 = *(const float4*)&hr[nbase + c0];
    float4 at4 = *(const float4*)&att[c0];
    int s0 = start[t * NP + i];
    int deg = cnt[t * NP + i];
    float l = 0.f;
    float4 acc = {0.f, 0.f, 0.f, 0.f};
    for (int base = 0; base < deg; base += 64) {
        int chunk = deg - base;
        chunk = (chunk < 64) ? chunk : 64;
        int stage = (lane < chunk) ? lane : 0;
        sidx[ws][lane] = ssrc[s0 + base + stage];
        int nfull = chunk & ~7;
        int j = 0;
        for (; j < nfull; j += 8) {          // unconditional: all 8 edges valid
            int src0 = sidx[ws][j + row];
            int src1 = sidx[ws][j + 4 + row];
            float4 h0 = *(const float4*)&hlt[((size_t)src0 << 6) + c0];
            float4 h1 = *(const float4*)&hlt[((size_t)src1 << 6) + c0];
            float4 z0, z1;
            z0.x = h0.x + r4.x; z0.y = h0.y + r4.y; z0.z = h0.z + r4.z; z0.w = h0.w + r4.w;
            z1.x = h1.x + r4.x; z1.y = h1.y + r4.y; z1.z = h1.z + r4.z; z1.w = h1.w + r4.w;
            z0.x = fmaxf(z0.x, LEAKY * z0.x); z0.y = fmaxf(z0.y, LEAKY * z0.y);
            z0.z = fmaxf(z0.z, LEAKY * z0.z); z0.w = fmaxf(z0.w, LEAKY * z0.w);
            z1.x = fmaxf(z1.x, LEAKY * z1.x); z1.y = fmaxf(z1.y, LEAKY * z1.y);
            z1.z = fmaxf(z1.z, LEAKY * z1.z); z1.w = fmaxf(z1.w, LEAKY * z1.w);
            float e0 = rowsum16(z0.x * at4.x + z0.y * at4.y + z0.z * at4.z + z0.w * at4.w);
            float e1 = rowsum16(z1.x * at4.x + z1.y * at4.y + z1.z * at4.z + z1.w * at4.w);
            float w0 = __expf(e0);
            float w1 = __expf(e1);
            l += w0 + w1;
            acc.x += w0 * h0.x + w1 * h1.x;
            acc.y += w0 * h0.y + w1 * h1.y;
            acc.z += w0 * h0.z + w1 * h1.z;
            acc.w += w0 * h0.w + w1 * h1.w;
        }
        for (; j < chunk; j += 4) {          // masked tail (<= 2 iters)
            int jj = j + row;
            int src = sidx[ws][(jj < chunk) ? jj : 0];
            float4 ha = *(const float4*)&hlt[((size_t)src << 6) + c0];
            float4 za;
            za.x = ha.x + r4.x; za.y = ha.y + r4.y; za.z = ha.z + r4.z; za.w = ha.w + r4.w;
            za.x = fmaxf(za.x, LEAKY * za.x);
            za.y = fmaxf(za.y, LEAKY * za.y);
            za.z = fmaxf(za.z, LEAKY * za.z);
            za.w = fmaxf(za.w, LEAKY * za.w);
            float ep = za.x * at4.x + za.y * at4.y + za.z * at4.z + za.w * at4.w;
            float e = rowsum16(ep);
            float w = __expf(e);
            w = (jj < chunk) ? w : 0.f;
            l += w;
            acc.x += w * ha.x; acc.y += w * ha.y; acc.z += w * ha.z; acc.w += w * ha.w;
        }
    }
    float lt = laneXorSum(l);
    acc.x = laneXorSum(acc.x);
    acc.y = laneXorSum(acc.y);
    acc.z = laneXorSum(acc.z);
    acc.w = laneXorSum(acc.w);
    if (row == 0) {
        float inv = (deg > 0) ? (1.0f / lt) : 0.f;
        float4 gb = *(const float4*)&gat_b[c0];
        float4 o;
        o.x = fmaxf(acc.x * inv + gb.x, 0.f);
        o.y = fmaxf(acc.y * inv + gb.y, 0.f);
        o.z = fmaxf(acc.z * inv + gb.z, 0.f);
        o.w = fmaxf(acc.w * inv + gb.w, 0.f);
        *(float4*)&hr[nbase + c0] = o;
    }
}

// ---- K4: Xhat @ W_timeT (+b_time) + rs, ReLU, LN ----
__global__ __launch_bounds__(256) void k_post(const float* __restrict__ Xhat,
        const float* __restrict__ wtT, const float* __restrict__ b_time,
        const float* __restrict__ rs, const float* __restrict__ ln_g,
        const float* __restrict__ ln_b, float* __restrict__ yn) {
    __shared__ float in_t[64][68];
    __shared__ float bk[64][68];
    int bx = blockIdx.x;
    int t = bx >> 6;
    int p0 = (bx & 63) * 64;
    int tid = threadIdx.x;
    const float4* src = (const float4*)(Xhat + ((size_t)t * NP + p0) * HG);
    for (int i4 = tid; i4 < 1024; i4 += 256) {
        int pp = i4 >> 4, c4 = (i4 & 15) * 4;
        *(float4*)&in_t[pp][c4] = src[i4];
    }
    const float4* wsrc = (const float4*)wtT;
    for (int i4 = tid; i4 < 1024; i4 += 256) {
        int h = i4 >> 4, c4 = (i4 & 15) * 4;
        *(float4*)&bk[h][c4] = wsrc[i4];
    }
    __syncthreads();
    int cg = tid & 15, pg = tid >> 4;
    int c0 = cg * 4, pl = pg * 4;
    float4 bt4 = *(const float4*)&b_time[c0];
    float acc[4][4];
#pragma unroll
    for (int i = 0; i < 4; ++i) {
        acc[i][0] = bt4.x; acc[i][1] = bt4.y; acc[i][2] = bt4.z; acc[i][3] = bt4.w;
    }
#pragma unroll
    for (int k4 = 0; k4 < 16; ++k4) {
        float4 A0 = *(const float4*)&in_t[pl + 0][k4 * 4];
        float4 A1 = *(const float4*)&in_t[pl + 1][k4 * 4];
        float4 A2 = *(const float4*)&in_t[pl + 2][k4 * 4];
        float4 A3 = *(const float4*)&in_t[pl + 3][k4 * 4];
        float4 B0 = *(const float4*)&bk[k4 * 4 + 0][c0];
        FMA4(A0.x, B0, 0) FMA4(A1.x, B0, 1) FMA4(A2.x, B0, 2) FMA4(A3.x, B0, 3)
        float4 B1 = *(const float4*)&bk[k4 * 4 + 1][c0];
        FMA4(A0.y, B1, 0) FMA4(A1.y, B1, 1) FMA4(A2.y, B1, 2) FMA4(A3.y, B1, 3)
        float4 B2 = *(const float4*)&bk[k4 * 4 + 2][c0];
        FMA4(A0.z, B2, 0) FMA4(A1.z, B2, 1) FMA4(A2.z, B2, 2) FMA4(A3.z, B2, 3)
        float4 B3 = *(const float4*)&bk[k4 * 4 + 3][c0];
        FMA4(A0.w, B3, 0) FMA4(A1.w, B3, 1) FMA4(A2.w, B3, 2) FMA4(A3.w, B3, 3)
    }
    float4 lg = *(const float4*)&ln_g[c0];
    float4 lb = *(const float4*)&ln_b[c0];
#pragma unroll
    for (int i = 0; i < 4; ++i) {
        size_t prow = (size_t)t * NP + p0 + pl + i;
        float4 r4 = *(const float4*)&rs[prow * NC + c0];
        float y0 = fmaxf(acc[i][0] + r4.x, 0.f), y1 = fmaxf(acc[i][1] + r4.y, 0.f);
        float y2 = fmaxf(acc[i][2] + r4.z, 0.f), y3 = fmaxf(acc[i][3] + r4.w, 0.f);
        float s = rowsum16(y0 + y1 + y2 + y3);
        float ss = rowsum16(y0 * y0 + y1 * y1 + y2 * y2 + y3 * y3);
        float mu = s * (1.f / 64.f);
        float var = ss * (1.f / 64.f) - mu * mu;
        float rsd = rsqrtf(var + LN_EPS);
        float4 o;
        o.x = (y0 - mu) * rsd * lg.x + lb.x;
        o.y = (y1 - mu) * rsd * lg.y + lb.y;
        o.z = (y2 - mu) * rsd * lg.z + lb.z;
        o.w = (y3 - mu) * rsd * lg.w + lb.w;
        *(float4*)&yn[prow * NC + c0] = o;
    }
}

// ---- K5: out[p,o] = sum_{t,c} yn[t,p,c] * Wf[o,t,c] + bf[o]; wave per p ----
__global__ __launch_bounds__(256) void k_final(const float* __restrict__ yn,
        const float* __restrict__ Wf, const float* __restrict__ bf,
        float* __restrict__ out) {
    int p = blockIdx.x * 4 + (threadIdx.x >> 6);
    int lane = threadIdx.x & 63;
    float acc[HOUT];
#pragma unroll
    for (int o = 0; o < HOUT; ++o) acc[o] = 0.f;
    for (int k = 0; k < NT; ++k) {
        float yv = yn[((size_t)k * NP + p) * NC + lane];
#pragma unroll
        for (int o = 0; o < HOUT; ++o)
            acc[o] += yv * Wf[(size_t)o * NT * NC + k * NC + lane];
    }
#pragma unroll
    for (int o = 0; o < HOUT; ++o) {
        float s = wavered63(acc[o]);
        if (lane == 0) out[p * HOUT + o] = s + bf[o];
    }
}

extern "C" void kernel_launch(void* const* d_in, const int* in_sizes, int n_in,
                              void* d_out, int out_size, void* d_ws, size_t ws_size,
                              hipStream_t stream) {
    const float* X      = (const float*)d_in[0];
    const int*   EI     = (const int*)d_in[1];
    const float* Wl     = (const float*)d_in[2];
    const float* Wr     = (const float*)d_in[3];
    const float* att    = (const float*)d_in[4];
    const float* gat_b  = (const float*)d_in[5];
    const float* W_time = (const float*)d_in[6];
    const float* b_time = (const float*)d_in[7];
    const float* W_res  = (const float*)d_in[8];
    const float* b_res  = (const float*)d_in[9];
    const float* ln_g   = (const float*)d_in[10];
    const float* ln_b   = (const float*)d_in[11];
    const float* Wf     = (const float*)d_in[12];
    const float* bf     = (const float*)d_in[13];
    float* out = (float*)d_out;

    char* ws = (char*)d_ws;
    const size_t MB = 1024 * 1024;
    float* hl    = (float*)(ws);                    // 32 MB (reused as yn)
    float* hr    = (float*)(ws + 32 * MB);          // 32 MB (becomes X_hat)
    float* rs    = (float*)(ws + 64 * MB);          // 32 MB residual
    int*   ssrc  = (int*)  (ws + 96 * MB);          // 8 MB
    int*   cnt   = (int*)  (ws + 104 * MB);         // 512 KB
    int*   strt  = (int*)  (ws + 104 * MB + 512 * 1024);
    float* wtT   = (float*)(ws + 105 * MB);         // 16 KB
    float* wrT   = (float*)(ws + 105 * MB + 16384);
    int*   cnt2  = (int*)  (ws + 106 * MB);         // 2 MB  [t][4][NP]
    int*   strt2 = (int*)  (ws + 108 * MB);         // 2 MB  [t][4][NP]
    float* yn    = hl;   // hl dead after k_gat

    k_prep <<<32, 256, 0, stream>>>(W_time, W_res, wtT, wrT);
    k_hlhr <<<NP / 2, 256, 0, stream>>>(X, Wl, Wr, wrT, b_res, hl, hr, rs);
    k_count<<<512, 256, 0, stream>>>(EI, cnt2);
    k_scan <<<NT, 256, 0, stream>>>(cnt2, cnt, strt, strt2);
    k_fill <<<512, 256, 0, stream>>>(EI, strt2, ssrc);
    k_gat  <<<(NT * NP) / 4, 256, 0, stream>>>(hl, hr, strt, cnt, ssrc, att, gat_b);
    k_post <<<NT * (NP / 64), 256, 0, stream>>>(hr, wtT, b_time, rs, ln_g, ln_b, yn);
    k_final<<<NP / 4, 256, 0, stream>>>(yn, Wf, bf, out);
}

// Round 10
// 284.038 us; speedup vs baseline: 1.7205x; 1.0232x over previous
//
#include <hip/hip_runtime.h>
#include <math.h>

#define NP 4096
#define F_IN 64
#define HG 64
#define NC 64
#define NT 32
#define NE 65536
#define HOUT 12
#define LEAKY 0.2f
#define LN_EPS 1e-5f

// ---- DPP reductions ----
template <int CTRL>
__device__ __forceinline__ float dppadd(float v, float x) {   // v + dpp(x); invalid lanes add 0
    int r = __builtin_amdgcn_update_dpp(0, __builtin_bit_cast(int, x), CTRL, 0xF, 0xF, false);
    return v + __builtin_bit_cast(float, r);
}
__device__ __forceinline__ float rowsum16(float v) {   // every lane gets its row-of-16 total
    v = dppadd<0x128>(v, v);   // row_ror:8
    v = dppadd<0x124>(v, v);   // row_ror:4
    v = dppadd<0x122>(v, v);   // row_ror:2
    v = dppadd<0x121>(v, v);   // row_ror:1
    return v;
}
__device__ __forceinline__ float xrowsum(float v) {    // ROW-UNIFORM input only! valid lanes 48-63
    v = dppadd<0x142>(v, v);   // row_bcast:15
    v = dppadd<0x143>(v, v);   // row_bcast:31
    return v;
}
__device__ __forceinline__ float rdlane(float v, int l) {
    return __builtin_bit_cast(float, __builtin_amdgcn_readlane(__builtin_bit_cast(int, v), l));
}
__device__ __forceinline__ float wavered63(float v) {
    v = rowsum16(v);
    v = xrowsum(v);
    return rdlane(v, 63);
}
__device__ __forceinline__ float laneXorSum(float v) { // lane-wise cross-row butterfly (16,32)
    v += __shfl_xor(v, 16, 64);
    v += __shfl_xor(v, 32, 64);
    return v;
}
__device__ __forceinline__ int waveSumInt(int v) {
#pragma unroll
    for (int d = 1; d < 64; d <<= 1) v += __shfl_xor(v, d, 64);
    return v;
}

#define FMA4(Acomp, B, r)                                                     \
    acc[r][0] += (Acomp) * (B).x; acc[r][1] += (Acomp) * (B).y;               \
    acc[r][2] += (Acomp) * (B).z; acc[r][3] += (Acomp) * (B).w;

// ---- K0: pre-transpose W_time/W_res ----
__global__ __launch_bounds__(256) void k_prep(const float* __restrict__ W_time,
        const float* __restrict__ W_res,
        float* __restrict__ wtT, float* __restrict__ wrT) {
    int b = blockIdx.x, tid = threadIdx.x;
    if (b < 16) {
        int i = b * 256 + tid;
        wtT[i] = W_time[(i & 63) * 64 + (i >> 6)];
    } else {
        int i = (b - 16) * 256 + tid;
        wrT[i] = W_res[(i & 63) * 64 + (i >> 6)];
    }
}

// ---- K1: hl|hr = X[p]^T @ [Wl|Wr]; rs = X[p]^T @ W_res^T + b_res ----
// 2 p per block; B staged in LDS; 52 KB LDS -> 3 blocks/CU
__global__ __launch_bounds__(256) void k_hlhr(const float* __restrict__ X,
        const float* __restrict__ Wl, const float* __restrict__ Wr,
        const float* __restrict__ wrT, const float* __restrict__ b_res,
        float* __restrict__ hl, float* __restrict__ hr, float* __restrict__ rs) {
    __shared__ float xs[2][F_IN][36];
    __shared__ float bk[F_IN][132];
    int p0 = blockIdx.x * 2, tid = threadIdx.x;
    const float4* Xp = (const float4*)(X + (size_t)p0 * F_IN * NT);
    for (int i4 = tid; i4 < 1024; i4 += 256) {
        int pp = i4 >> 9, f = (i4 >> 3) & 63, t0 = (i4 & 7) * 4;
        *(float4*)&xs[pp][f][t0] = Xp[i4];
    }
    for (int i = tid; i < F_IN * HG; i += 256) {
        int f = i >> 6, h = i & 63;
        bk[f][h] = Wl[i];
        bk[f][64 + h] = Wr[i];
    }
    __syncthreads();
    {
        int ng = tid & 31, tg = tid >> 5;
        int n0 = ng * 4, col = (ng & 15) * 4, t0 = tg * 4;
        float acc[8][4];
#pragma unroll
        for (int i = 0; i < 8; ++i)
#pragma unroll
            for (int j = 0; j < 4; ++j) acc[i][j] = 0.f;
#pragma unroll 4
        for (int f = 0; f < F_IN; ++f) {
            float4 B = *(const float4*)&bk[f][n0];
            float4 A0 = *(const float4*)&xs[0][f][t0];
            float4 A1 = *(const float4*)&xs[1][f][t0];
            FMA4(A0.x, B, 0) FMA4(A0.y, B, 1) FMA4(A0.z, B, 2) FMA4(A0.w, B, 3)
            FMA4(A1.x, B, 4) FMA4(A1.y, B, 5) FMA4(A1.z, B, 6) FMA4(A1.w, B, 7)
        }
#pragma unroll
        for (int pp = 0; pp < 2; ++pp) {
#pragma unroll
            for (int i = 0; i < 4; ++i) {
                size_t rb = ((size_t)(t0 + i) * NP + p0 + pp) * HG;
                float4 v;
                v.x = acc[pp * 4 + i][0]; v.y = acc[pp * 4 + i][1];
                v.z = acc[pp * 4 + i][2]; v.w = acc[pp * 4 + i][3];
                if (ng < 16) *(float4*)&hl[rb + col] = v;
                else         *(float4*)&hr[rb + col] = v;
            }
        }
    }
    __syncthreads();
    for (int i = tid; i < F_IN * NC; i += 256) bk[i >> 6][i & 63] = wrT[i];
    __syncthreads();
    {
        int cg = tid & 15, tg = tid >> 4;
        int c0 = cg * 4, t0 = tg * 2;
        float4 br4 = *(const float4*)&b_res[c0];
        float acc[4][4];
#pragma unroll
        for (int i = 0; i < 4; ++i) {
            acc[i][0] = br4.x; acc[i][1] = br4.y; acc[i][2] = br4.z; acc[i][3] = br4.w;
        }
#pragma unroll 4
        for (int f = 0; f < F_IN; ++f) {
            float4 B = *(const float4*)&bk[f][c0];
            float2 A0 = *(const float2*)&xs[0][f][t0];
            float2 A1 = *(const float2*)&xs[1][f][t0];
            FMA4(A0.x, B, 0) FMA4(A0.y, B, 1)
            FMA4(A1.x, B, 2) FMA4(A1.y, B, 3)
        }
#pragma unroll
        for (int pp = 0; pp < 2; ++pp) {
#pragma unroll
            for (int i = 0; i < 2; ++i) {
                float4 v;
                v.x = acc[pp * 2 + i][0]; v.y = acc[pp * 2 + i][1];
                v.z = acc[pp * 2 + i][2]; v.w = acc[pp * 2 + i][3];
                *(float4*)&rs[((size_t)(t0 + i) * NP + p0 + pp) * NC + c0] = v;
            }
        }
    }
}

// ---- K2a: per-(t,c,r) counts into cnt2[t][c][d] + per-256-dst segment sums ----
__global__ __launch_bounds__(256) void k_count(const int* __restrict__ EI,
        int* __restrict__ cnt2, int* __restrict__ segsum2) {
    __shared__ int loc[1024];
    int b = blockIdx.x;
    int j = b >> 3;
    int t = (b & 7) + 8 * (j & 3);
    int cr = j >> 2;
    int c = cr & 3, r = cr >> 2;
    int tid = threadIdx.x;
    loc[tid] = 0; loc[tid + 256] = 0; loc[tid + 512] = 0; loc[tid + 768] = 0;
    __syncthreads();
    int base = r << 10;
    const int4* dstA = (const int4*)(EI + (size_t)t * 2 * NE + NE) + c * (NE / 16);
    for (int i = tid; i < NE / 16; i += 256) {
        int4 d = dstA[i];
        if ((d.x >> 10) == r) atomicAdd(&loc[d.x - base], 1);
        if ((d.y >> 10) == r) atomicAdd(&loc[d.y - base], 1);
        if ((d.z >> 10) == r) atomicAdd(&loc[d.z - base], 1);
        if ((d.w >> 10) == r) atomicAdd(&loc[d.w - base], 1);
    }
    __syncthreads();
    int o = (t * 4 + c) * NP + base + tid;
    cnt2[o] = loc[tid];
    cnt2[o + 256] = loc[tid + 256];
    cnt2[o + 512] = loc[tid + 512];
    cnt2[o + 768] = loc[tid + 768];
    // segment sums: wave wv reduces loc[wv*256 .. +255]
    int wv = tid >> 6, lane = tid & 63;
    int s = loc[wv * 256 + lane] + loc[wv * 256 + lane + 64]
          + loc[wv * 256 + lane + 128] + loc[wv * 256 + lane + 192];
    s = waveSumInt(s);
    if (lane == 0) segsum2[(t * 4 + c) * 16 + r * 4 + wv] = s;
}

// ---- K2b: scan; block = (t, 256-dst segment); 512 blocks, all coalesced ----
__global__ __launch_bounds__(256) void k_scan(const int* __restrict__ cnt2,
        const int* __restrict__ segsum2, int* __restrict__ cnt,
        int* __restrict__ start, int* __restrict__ start2) {
    __shared__ int sc[256];
    __shared__ int preS;
    int b = blockIdx.x;
    int t = b >> 4, seg = b & 15;
    int tid = threadIdx.x;
    if (tid < 64) {                          // first wave: prefix of earlier segments
        int c = tid >> 4, s = tid & 15;
        int v = (s < seg) ? segsum2[(t * 4 + c) * 16 + s] : 0;
        v = waveSumInt(v);
        if (tid == 0) preS = v;
    }
    int d = seg * 256 + tid;
    int q0 = cnt2[(t * 4 + 0) * NP + d];
    int q1 = cnt2[(t * 4 + 1) * NP + d];
    int q2 = cnt2[(t * 4 + 2) * NP + d];
    int q3 = cnt2[(t * 4 + 3) * NP + d];
    int deg = q0 + q1 + q2 + q3;
    sc[tid] = deg;
    __syncthreads();
    int pre = preS;
    for (int dd = 1; dd < 256; dd <<= 1) {
        int v = (tid >= dd) ? sc[tid - dd] : 0;
        __syncthreads();
        sc[tid] += v;
        __syncthreads();
    }
    int exc = sc[tid] - deg;
    int st = t * NE + pre + exc;
    cnt[t * NP + d] = deg;
    start[t * NP + d] = st;
    start2[(t * 4 + 0) * NP + d] = st; st += q0;
    start2[(t * 4 + 1) * NP + d] = st; st += q1;
    start2[(t * 4 + 2) * NP + d] = st; st += q2;
    start2[(t * 4 + 3) * NP + d] = st;
}

// ---- K2c: fill from per-(t,c) cursors; block-local LDS atomics only ----
__global__ __launch_bounds__(256) void k_fill(const int* __restrict__ EI,
        const int* __restrict__ start2, int* __restrict__ ssrc) {
    __shared__ int curs_l[1024];
    int b = blockIdx.x;
    int j = b >> 3;
    int t = (b & 7) + 8 * (j & 3);
    int cr = j >> 2;
    int c = cr & 3, r = cr >> 2;
    int tid = threadIdx.x;
    int base = r << 10;
    int o = (t * 4 + c) * NP + base + tid;
    curs_l[tid] = start2[o];
    curs_l[tid + 256] = start2[o + 256];
    curs_l[tid + 512] = start2[o + 512];
    curs_l[tid + 768] = start2[o + 768];
    __syncthreads();
    const int4* srcA = (const int4*)(EI + (size_t)t * 2 * NE) + c * (NE / 16);
    const int4* dstA = (const int4*)(EI + (size_t)t * 2 * NE + NE) + c * (NE / 16);
    for (int i = tid; i < NE / 16; i += 256) {
        int4 s = srcA[i];
        int4 d = dstA[i];
        if ((d.x >> 10) == r) { int sl = atomicAdd(&curs_l[d.x - base], 1); ssrc[sl] = s.x; }
        if ((d.y >> 10) == r) { int sl = atomicAdd(&curs_l[d.y - base], 1); ssrc[sl] = s.y; }
        if ((d.z >> 10) == r) { int sl = atomicAdd(&curs_l[d.z - base], 1); ssrc[sl] = s.z; }
        if ((d.w >> 10) == r) { int sl = atomicAdd(&curs_l[d.w - base], 1); ssrc[sl] = s.w; }
    }
}

// ---- K3: GATv2; wave per dst; 8 edges/iter (2 independent 4-edge chains) ----
__global__ __launch_bounds__(256) void k_gat(const float* __restrict__ hl,
        float* __restrict__ hr,
        const int* __restrict__ start, const int* __restrict__ cnt,
        const int* __restrict__ ssrc,
        const float* __restrict__ att, const float* __restrict__ gat_b) {
    __shared__ int sidx[4][64];
    int b = blockIdx.x;              // 32768 blocks
    int k = b >> 3;                  // 0..4095
    int t = (b & 7) + 8 * (k >> 10); // one t per XCD at a time
    int ws = threadIdx.x >> 6;
    int i = (k & 1023) * 4 + ws;
    int lane = threadIdx.x & 63;
    int row = lane >> 4;
    int c0 = (lane & 15) * 4;
    size_t nbase = ((size_t)t * NP + i) * HG;
    const float* hlt = hl + (size_t)t * NP * HG;
    float4 r4 = *(const float4*)&hr[nbase + c0];
    float4 at4 = *(const float4*)&att[c0];
    int s0 = start[t * NP + i];
    int deg = cnt[t * NP + i];
    float l = 0.f;
    float4 acc = {0.f, 0.f, 0.f, 0.f};
    for (int base = 0; base < deg; base += 64) {
        int chunk = deg - base;
        chunk = (chunk < 64) ? chunk : 64;
        int stage = (lane < chunk) ? lane : 0;
        sidx[ws][lane] = ssrc[s0 + base + stage];
        int nfull = chunk & ~7;
        int j = 0;
        for (; j < nfull; j += 8) {
            int src0 = sidx[ws][j + row];
            int src1 = sidx[ws][j + 4 + row];
            float4 h0 = *(const float4*)&hlt[((size_t)src0 << 6) + c0];
            float4 h1 = *(const float4*)&hlt[((size_t)src1 << 6) + c0];
            float4 z0, z1;
            z0.x = h0.x + r4.x; z0.y = h0.y + r4.y; z0.z = h0.z + r4.z; z0.w = h0.w + r4.w;
            z1.x = h1.x + r4.x; z1.y = h1.y + r4.y; z1.z = h1.z + r4.z; z1.w = h1.w + r4.w;
            z0.x = fmaxf(z0.x, LEAKY * z0.x); z0.y = fmaxf(z0.y, LEAKY * z0.y);
            z0.z = fmaxf(z0.z, LEAKY * z0.z); z0.w = fmaxf(z0.w, LEAKY * z0.w);
            z1.x = fmaxf(z1.x, LEAKY * z1.x); z1.y = fmaxf(z1.y, LEAKY * z1.y);
            z1.z = fmaxf(z1.z, LEAKY * z1.z); z1.w = fmaxf(z1.w, LEAKY * z1.w);
            float e0 = rowsum16(z0.x * at4.x + z0.y * at4.y + z0.z * at4.z + z0.w * at4.w);
            float e1 = rowsum16(z1.x * at4.x + z1.y * at4.y + z1.z * at4.z + z1.w * at4.w);
            float w0 = __expf(e0);
            float w1 = __expf(e1);
            l += w0 + w1;
            acc.x += w0 * h0.x + w1 * h1.x;
            acc.y += w0 * h0.y + w1 * h1.y;
            acc.z += w0 * h0.z + w1 * h1.z;
            acc.w += w0 * h0.w + w1 * h1.w;
        }
        for (; j < chunk; j += 4) {
            int jj = j + row;
            int src = sidx[ws][(jj < chunk) ? jj : 0];
            float4 ha = *(const float4*)&hlt[((size_t)src << 6) + c0];
            float4 za;
            za.x = ha.x + r4.x; za.y = ha.y + r4.y; za.z = ha.z + r4.z; za.w = ha.w + r4.w;
            za.x = fmaxf(za.x, LEAKY * za.x);
            za.y = fmaxf(za.y, LEAKY * za.y);
            za.z = fmaxf(za.z, LEAKY * za.z);
            za.w = fmaxf(za.w, LEAKY * za.w);
            float ep = za.x * at4.x + za.y * at4.y + za.z * at4.z + za.w * at4.w;
            float e = rowsum16(ep);
            float w = __expf(e);
            w = (jj < chunk) ? w : 0.f;
            l += w;
            acc.x += w * ha.x; acc.y += w * ha.y; acc.z += w * ha.z; acc.w += w * ha.w;
        }
    }
    float lt = laneXorSum(l);
    acc.x = laneXorSum(acc.x);
    acc.y = laneXorSum(acc.y);
    acc.z = laneXorSum(acc.z);
    acc.w = laneXorSum(acc.w);
    if (row == 0) {
        float inv = (deg > 0) ? (1.0f / lt) : 0.f;
        float4 gb = *(const float4*)&gat_b[c0];
        float4 o;
        o.x = fmaxf(acc.x * inv + gb.x, 0.f);
        o.y = fmaxf(acc.y * inv + gb.y, 0.f);
        o.z = fmaxf(acc.z * inv + gb.z, 0.f);
        o.w = fmaxf(acc.w * inv + gb.w, 0.f);
        *(float4*)&hr[nbase + c0] = o;
    }
}

// ---- K4: Xhat @ W_timeT (+b_time) + rs, ReLU, LN; XCD-swizzled (t ≡ xcd) ----
__global__ __launch_bounds__(256) void k_post(const float* __restrict__ Xhat,
        const float* __restrict__ wtT, const float* __restrict__ b_time,
        const float* __restrict__ rs, const float* __restrict__ ln_g,
        const float* __restrict__ ln_b, float* __restrict__ yn) {
    __shared__ float in_t[64][68];
    __shared__ float bk[64][68];
    int bx = blockIdx.x;             // 2048; j=bx>>3: t=(bx&7)+8*(j&3), ptile=j>>2
    int j = bx >> 3;
    int t = (bx & 7) + 8 * (j & 3);
    int p0 = (j >> 2) * 64;
    int tid = threadIdx.x;
    const float4* src = (const float4*)(Xhat + ((size_t)t * NP + p0) * HG);
    for (int i4 = tid; i4 < 1024; i4 += 256) {
        int pp = i4 >> 4, c4 = (i4 & 15) * 4;
        *(float4*)&in_t[pp][c4] = src[i4];
    }
    const float4* wsrc = (const float4*)wtT;
    for (int i4 = tid; i4 < 1024; i4 += 256) {
        int h = i4 >> 4, c4 = (i4 & 15) * 4;
        *(float4*)&bk[h][c4] = wsrc[i4];
    }
    __syncthreads();
    int cg = tid & 15, pg = tid >> 4;
    int c0 = cg * 4, pl = pg * 4;
    float4 bt4 = *(const float4*)&b_time[c0];
    float acc[4][4];
#pragma unroll
    for (int i = 0; i < 4; ++i) {
        acc[i][0] = bt4.x; acc[i][1] = bt4.y; acc[i][2] = bt4.z; acc[i][3] = bt4.w;
    }
#pragma unroll
    for (int k4 = 0; k4 < 16; ++k4) {
        float4 A0 = *(const float4*)&in_t[pl + 0][k4 * 4];
        float4 A1 = *(const float4*)&in_t[pl + 1][k4 * 4];
        float4 A2 = *(const float4*)&in_t[pl + 2][k4 * 4];
        float4 A3 = *(const float4*)&in_t[pl + 3][k4 * 4];
        float4 B0 = *(const float4*)&bk[k4 * 4 + 0][c0];
        FMA4(A0.x, B0, 0) FMA4(A1.x, B0, 1) FMA4(A2.x, B0, 2) FMA4(A3.x, B0, 3)
        float4 B1 = *(const float4*)&bk[k4 * 4 + 1][c0];
        FMA4(A0.y, B1, 0) FMA4(A1.y, B1, 1) FMA4(A2.y, B1, 2) FMA4(A3.y, B1, 3)
        float4 B2 = *(const float4*)&bk[k4 * 4 + 2][c0];
        FMA4(A0.z, B2, 0) FMA4(A1.z, B2, 1) FMA4(A2.z, B2, 2) FMA4(A3.z, B2, 3)
        float4 B3 = *(const float4*)&bk[k4 * 4 + 3][c0];
        FMA4(A0.w, B3, 0) FMA4(A1.w, B3, 1) FMA4(A2.w, B3, 2) FMA4(A3.w, B3, 3)
    }
    float4 lg = *(const float4*)&ln_g[c0];
    float4 lb = *(const float4*)&ln_b[c0];
#pragma unroll
    for (int i = 0; i < 4; ++i) {
        size_t prow = (size_t)t * NP + p0 + pl + i;
        float4 r4 = *(const float4*)&rs[prow * NC + c0];
        float y0 = fmaxf(acc[i][0] + r4.x, 0.f), y1 = fmaxf(acc[i][1] + r4.y, 0.f);
        float y2 = fmaxf(acc[i][2] + r4.z, 0.f), y3 = fmaxf(acc[i][3] + r4.w, 0.f);
        float s = rowsum16(y0 + y1 + y2 + y3);
        float ss = rowsum16(y0 * y0 + y1 * y1 + y2 * y2 + y3 * y3);
        float mu = s * (1.f / 64.f);
        float var = ss * (1.f / 64.f) - mu * mu;
        float rsd = rsqrtf(var + LN_EPS);
        float4 o;
        o.x = (y0 - mu) * rsd * lg.x + lb.x;
        o.y = (y1 - mu) * rsd * lg.y + lb.y;
        o.z = (y2 - mu) * rsd * lg.z + lb.z;
        o.w = (y3 - mu) * rsd * lg.w + lb.w;
        *(float4*)&yn[prow * NC + c0] = o;
    }
}

// ---- K5: out[p,o] = sum_{t,c} yn[t,p,c] * Wf[o,t,c] + bf[o]; wave per p ----
__global__ __launch_bounds__(256) void k_final(const float* __restrict__ yn,
        const float* __restrict__ Wf, const float* __restrict__ bf,
        float* __restrict__ out) {
    int p = blockIdx.x * 4 + (threadIdx.x >> 6);
    int lane = threadIdx.x & 63;
    float acc[HOUT];
#pragma unroll
    for (int o = 0; o < HOUT; ++o) acc[o] = 0.f;
    for (int k = 0; k < NT; ++k) {
        float yv = yn[((size_t)k * NP + p) * NC + lane];
#pragma unroll
        for (int o = 0; o < HOUT; ++o)
            acc[o] += yv * Wf[(size_t)o * NT * NC + k * NC + lane];
    }
#pragma unroll
    for (int o = 0; o < HOUT; ++o) {
        float s = wavered63(acc[o]);
        if (lane == 0) out[p * HOUT + o] = s + bf[o];
    }
}

extern "C" void kernel_launch(void* const* d_in, const int* in_sizes, int n_in,
                              void* d_out, int out_size, void* d_ws, size_t ws_size,
                              hipStream_t stream) {
    const float* X      = (const float*)d_in[0];
    const int*   EI     = (const int*)d_in[1];
    const float* Wl     = (const float*)d_in[2];
    const float* Wr     = (const float*)d_in[3];
    const float* att    = (const float*)d_in[4];
    const float* gat_b  = (const float*)d_in[5];
    const float* W_time = (const float*)d_in[6];
    const float* b_time = (const float*)d_in[7];
    const float* W_res  = (const float*)d_in[8];
    const float* b_res  = (const float*)d_in[9];
    const float* ln_g   = (const float*)d_in[10];
    const float* ln_b   = (const float*)d_in[11];
    const float* Wf     = (const float*)d_in[12];
    const float* bf     = (const float*)d_in[13];
    float* out = (float*)d_out;

    char* ws = (char*)d_ws;
    const size_t MB = 1024 * 1024;
    float* hl    = (float*)(ws);                    // 32 MB (reused as yn)
    float* hr    = (float*)(ws + 32 * MB);          // 32 MB (becomes X_hat)
    float* rs    = (float*)(ws + 64 * MB);          // 32 MB residual
    int*   ssrc  = (int*)  (ws + 96 * MB);          // 8 MB
    int*   cnt   = (int*)  (ws + 104 * MB);         // 512 KB
    int*   strt  = (int*)  (ws + 104 * MB + 512 * 1024);
    float* wtT   = (float*)(ws + 105 * MB);         // 16 KB
    float* wrT   = (float*)(ws + 105 * MB + 16384);
    int*   segs2 = (int*)  (ws + 105 * MB + 32768); // 8 KB [t][c][16]
    int*   cnt2  = (int*)  (ws + 106 * MB);         // 2 MB  [t][4][NP]
    int*   strt2 = (int*)  (ws + 108 * MB);         // 2 MB  [t][4][NP]
    float* yn    = hl;   // hl dead after k_gat

    k_prep <<<32, 256, 0, stream>>>(W_time, W_res, wtT, wrT);
    k_hlhr <<<NP / 2, 256, 0, stream>>>(X, Wl, Wr, wrT, b_res, hl, hr, rs);
    k_count<<<512, 256, 0, stream>>>(EI, cnt2, segs2);
    k_scan <<<NT * 16, 256, 0, stream>>>(cnt2, segs2, cnt, strt, strt2);
    k_fill <<<512, 256, 0, stream>>>(EI, strt2, ssrc);
    k_gat  <<<(NT * NP) / 4, 256, 0, stream>>>(hl, hr, strt, cnt, ssrc, att, gat_b);
    k_post <<<NT * (NP / 64), 256, 0, stream>>>(hr, wtT, b_time, rs, ln_g, ln_b, yn);
    k_final<<<NP / 4, 256, 0, stream>>>(yn, Wf, bf, out);
}